// Round 2
// baseline (654.447 us; speedup 1.0000x reference)
//
#include <hip/hip_runtime.h>
#include <hip/hip_bf16.h>
#include <math.h>
#include <stddef.h>

// Problem constants (from reference)
#define NB 8
#define NT 1024
#define NF 80
#define NSTACK 4
#define NSTRIDE 4
#define NG 4
#define NE 16
#define NC 8192
#define ND 512
#define NTS 256          // (NT-NSTACK)/NSTRIDE + 1
#define NP (NB*NTS)      // 2048 subsampled positions
#define SFD (NSTACK*NF)  // 320
#define FREG 0.01f
#define LNEPS 1e-5f

// fp32-fallback k_logits tiling
#define TCC 1024
#define CPT 4
#define PCH 16
#define PB 16

// MFMA path
#define ROWS_MAX 2176     // ceil(2048/144)*144 = 2160, padded
#define MT 9              // m-tiles per super-pass (144 rows)
#define QCH 128           // lat rows staged per k_qdist pass

typedef __attribute__((ext_vector_type(8))) short short8;
typedef __attribute__((ext_vector_type(4))) float f32x4;

struct Ws {
  float penSum;
  unsigned int nA;
  unsigned int maskIsInt;
  unsigned int pad1;
  unsigned long long amax[NP*NG];   // packed (key<<32 | ~idx) argmax
  unsigned long long amin[NP*NG];   // packed (key<<32 | idx) argmin (quantize)
  float sumExp[NP*NG];
  float tLogit[NP*NG];
  int   targets[NP*NG];
  int   activeList[NP];
  unsigned int bitmap[NC/32];
  // --- MFMA-path extension (zero region ends at lat) ---
  float lat[NP][64];
  unsigned short aHi[(size_t)ROWS_MAX*ND];
  unsigned short aLo[(size_t)ROWS_MAX*ND];
};

__device__ inline unsigned short bf16_rne(float x) {
  unsigned u = __float_as_uint(x);
  unsigned r = u + 0x7FFFu + ((u >> 16) & 1u);
  return (unsigned short)(r >> 16);
}
__device__ inline unsigned fkey_asc(float d) {  // ascending float -> ascending uint
  unsigned u = __float_as_uint(d);
  return (u & 0x80000000u) ? ~u : (u | 0x80000000u);
}

// ---- detect whether masks buffer is uint8 (numpy bool) or int32 ----
__global__ void k_detect(const unsigned char* __restrict__ m, Ws* ws) {
  __shared__ unsigned flag;
  if (threadIdx.x == 0) flag = 0;
  __syncthreads();
  unsigned nz = 0;
  int base = threadIdx.x * 32;
  for (int i = base; i < base + 32; ++i)
    if ((i & 3) && m[i]) nz = 1;
  if (nz) atomicOr(&flag, 1u);
  __syncthreads();
  if (threadIdx.x == 0) ws->maskIsInt = (flag ? 0u : 1u);
}

// ---- features_pen ----
__global__ void k_pen(const float* __restrict__ feats,
                      const float* __restrict__ mean,
                      const float* __restrict__ istd, Ws* ws) {
  const int N4 = NB*NT*NF/4;
  float s = 0.f;
  for (int i = blockIdx.x*blockDim.x + threadIdx.x; i < N4; i += gridDim.x*blockDim.x) {
    float4 v = reinterpret_cast<const float4*>(feats)[i];
    int f0 = (i*4) % NF;
    float x0 = (v.x - mean[f0+0]) * istd[f0+0];
    float x1 = (v.y - mean[f0+1]) * istd[f0+1];
    float x2 = (v.z - mean[f0+2]) * istd[f0+2];
    float x3 = (v.w - mean[f0+3]) * istd[f0+3];
    s += x0*x0 + x1*x1 + x2*x2 + x3*x3;
  }
  for (int o = 32; o; o >>= 1) s += __shfl_down(s, o);
  if ((threadIdx.x & 63) == 0) atomicAdd(&ws->penSum, s);
}

// ---- mask + compact ----
__global__ void k_mask(const unsigned char* __restrict__ m8,
                       const int* __restrict__ lens, Ws* ws) {
  int p = blockIdx.x*blockDim.x + threadIdx.x;
  if (p >= NP) return;
  int b = p >> 8, ts = p & (NTS-1);
  int t0 = b*NT + ts*NSTRIDE;
  bool allm;
  if (ws->maskIsInt) {
    const int* m32 = (const int*)m8;
    allm = m32[t0] && m32[t0+1] && m32[t0+2] && m32[t0+3];
  } else {
    allm = m8[t0] && m8[t0+1] && m8[t0+2] && m8[t0+3];
  }
  int ls = (lens[b] - NSTACK)/NSTRIDE + 1;
  if (ls < 0) ls = 0;
  if (allm && ts < ls) {
    unsigned idx = atomicAdd(&ws->nA, 1u);
    ws->activeList[idx] = p;
  }
}

// ---- latents: stack + LayerNorm + projection -> ws->lat[ai][64] ----
__global__ __launch_bounds__(256) void k_latent(
    const float* __restrict__ feats, const float* __restrict__ mean,
    const float* __restrict__ istd, const float* __restrict__ projw, Ws* ws) {
  if (blockIdx.x >= ws->nA) return;
  int ai = blockIdx.x;
  int p = ws->activeList[ai];
  int b = p >> 8, ts = p & (NTS-1);
  int tid = threadIdx.x;
  __shared__ float sN[SFD];
  __shared__ float sPart[4*64];
  __shared__ float rS[4], rQ[4];

  for (int j = tid; j < SFD; j += 256) {
    int k = j / NF, f = j - k*NF;
    sN[j] = (feats[((size_t)b*NT + ts*NSTRIDE + k)*NF + f] - mean[f]) * istd[f];
  }
  __syncthreads();
  float s = 0.f, q = 0.f;
  for (int j = tid; j < SFD; j += 256) { float x = sN[j]; s += x; q += x*x; }
  for (int o = 32; o; o >>= 1) { s += __shfl_down(s, o); q += __shfl_down(q, o); }
  if ((tid & 63) == 0) { rS[tid>>6] = s; rQ[tid>>6] = q; }
  __syncthreads();
  float mu  = (rS[0]+rS[1]+rS[2]+rS[3]) * (1.f/SFD);
  float var = (rQ[0]+rQ[1]+rQ[2]+rQ[3]) * (1.f/SFD) - mu*mu;
  float inv = rsqrtf(var + LNEPS);
  for (int j = tid; j < SFD; j += 256) sN[j] = (sN[j]-mu)*inv;
  __syncthreads();
  {
    int j = tid & 63, part = tid >> 6;
    float a = 0.f;
    int i0 = part*80;
    for (int i = i0; i < i0+80; ++i) a = fmaf(sN[i], projw[i*64 + j], a);
    sPart[part*64 + j] = a;
  }
  __syncthreads();
  if (tid < 64)
    ws->lat[ai][tid] = sPart[tid] + sPart[64+tid] + sPart[128+tid] + sPart[192+tid];
}

// ---- codebook argmin, c-parallel; exact first-min ties via packed atomicMin ----
__global__ __launch_bounds__(256) void k_qdist(const float* __restrict__ emb, Ws* ws) {
  int nA = (int)ws->nA;
  if (nA == 0) return;
  int tid = threadIdx.x;
  int g = tid >> 6, lane = tid & 63;
  int c = blockIdx.x * 64 + lane;
  int per = (nA + 1) >> 1;
  int a0 = blockIdx.y * per;
  int a1 = min(nA, a0 + per);

  const float4* e4 = reinterpret_cast<const float4*>(emb + ((size_t)c*NG + g)*NE);
  float4 b0 = e4[0], b1 = e4[1], b2 = e4[2], b3 = e4[3];
  float n2 = b0.x*b0.x + b0.y*b0.y + b0.z*b0.z + b0.w*b0.w
           + b1.x*b1.x + b1.y*b1.y + b1.z*b1.z + b1.w*b1.w
           + b2.x*b2.x + b2.y*b2.y + b2.z*b2.z + b2.w*b2.w
           + b3.x*b3.x + b3.y*b3.y + b3.z*b3.z + b3.w*b3.w;

  __shared__ float sL[QCH][64];
  for (int base = a0; base < a1; base += QCH) {
    int cnt = min(QCH, a1 - base);
    __syncthreads();
    for (int i = tid; i < cnt*64; i += 256)
      (&sL[0][0])[i] = (&ws->lat[0][0])[(size_t)(base + (i >> 6))*64 + (i & 63)];
    __syncthreads();
    for (int i = 0; i < cnt; ++i) {
      const float* lp = &sL[i][g*NE];
      float dot = lp[0]*b0.x + lp[1]*b0.y + lp[2]*b0.z + lp[3]*b0.w
                + lp[4]*b1.x + lp[5]*b1.y + lp[6]*b1.z + lp[7]*b1.w
                + lp[8]*b2.x + lp[9]*b2.y + lp[10]*b2.z + lp[11]*b2.w
                + lp[12]*b3.x + lp[13]*b3.y + lp[14]*b3.z + lp[15]*b3.w;
      float d = n2 - 2.f*dot;
      float mv = d; int mc = c;
      #pragma unroll
      for (int off = 32; off; off >>= 1) {
        float ov = __shfl_xor(mv, off);
        int   oc = __shfl_xor(mc, off);
        if (ov < mv || (ov == mv && oc < mc)) { mv = ov; mc = oc; }
      }
      if (lane == 0) {
        unsigned long long key =
            ((unsigned long long)fkey_asc(mv) << 32) | (unsigned)mc;
        atomicMin(&ws->amin[(base + i)*NG + g], key);
      }
    }
  }
}

// ---- extract targets + uniq bitmap ----
__global__ void k_tgt(Ws* ws) {
  int i = blockIdx.x*256 + threadIdx.x;
  int nA = (int)ws->nA;
  if (i < nA*NG) {
    int c = (int)(unsigned)(ws->amin[i] & 0xFFFFFFFFull);
    ws->targets[i] = c;
    atomicOr(&ws->bitmap[c >> 5], 1u << (c & 31));
  }
}

// ---- precompute bf16 hi/lo splits of active encoder rows (zero-padded) ----
__global__ void k_prepA(const float* __restrict__ enc, Ws* ws) {
  int ai = blockIdx.x;
  int nA = (int)ws->nA;
  int limit = ((nA + (MT*16 - 1)) / (MT*16)) * (MT*16);
  if (ai >= limit) return;
  int lane = threadIdx.x;  // 64 threads
  const float* src = (ai < nA) ? enc + (size_t)ws->activeList[ai]*ND : nullptr;
  for (int t = 0; t < ND/64; ++t) {
    int d = t*64 + lane;
    float x = (ai < nA) ? src[d] : 0.f;
    unsigned short hi = bf16_rne(x);
    float rem = x - __uint_as_float((unsigned)hi << 16);
    unsigned short lo = bf16_rne(rem);
    ws->aHi[(size_t)ai*ND + d] = hi;
    ws->aLo[(size_t)ai*ND + d] = lo;
  }
}

// ---- logits GEMM via MFMA bf16 3-product split + fused logsumexp/argmax ----
__global__ __launch_bounds__(256) void k_logits_mfma(
    const float* __restrict__ W, const float* __restrict__ bias, Ws* ws) {
  const int nA = (int)ws->nA;
  if (nA == 0) return;
  const int nSup = (nA + (MT*16 - 1)) / (MT*16);
  const int tid = threadIdx.x;
  const int wave = tid >> 6, lane = tid & 63;
  const int g = blockIdx.y;
  const int c0 = blockIdx.x * 64 + wave * 16;
  const int cl = c0 + (lane & 15);
  const int klane = (lane >> 4) * 8;
  const float bv = bias[g*NC + cl];

  for (int sup = 0; sup < nSup; ++sup) {
    const int base_m = sup * (MT*16);
    f32x4 acc[MT];
    #pragma unroll
    for (int mt = 0; mt < MT; ++mt) acc[mt] = (f32x4){0.f, 0.f, 0.f, 0.f};

    for (int ks = 0; ks < ND/32; ++ks) {
      const int k0 = ks * 32;
      // B fragment: W[g][k0+klane+j][cl], j=0..7 -> bf16 hi/lo
      const float* wp = W + ((size_t)g*ND + k0 + klane)*NC + cl;
      float wv[8];
      #pragma unroll
      for (int j = 0; j < 8; ++j) wv[j] = wp[(size_t)j*NC];
      short8 whi, wlo;
      #pragma unroll
      for (int j = 0; j < 8; ++j) {
        unsigned short h = bf16_rne(wv[j]);
        float rem = wv[j] - __uint_as_float((unsigned)h << 16);
        whi[j] = (short)h;
        wlo[j] = (short)bf16_rne(rem);
      }
      const size_t aoff = (size_t)(base_m + (lane & 15))*ND + k0 + klane;
      #pragma unroll
      for (int mt = 0; mt < MT; ++mt) {
        short8 ahi = *reinterpret_cast<const short8*>(ws->aHi + aoff + (size_t)mt*16*ND);
        short8 alo = *reinterpret_cast<const short8*>(ws->aLo + aoff + (size_t)mt*16*ND);
        acc[mt] = __builtin_amdgcn_mfma_f32_16x16x32_bf16(ahi, whi, acc[mt], 0, 0, 0);
        acc[mt] = __builtin_amdgcn_mfma_f32_16x16x32_bf16(ahi, wlo, acc[mt], 0, 0, 0);
        acc[mt] = __builtin_amdgcn_mfma_f32_16x16x32_bf16(alo, whi, acc[mt], 0, 0, 0);
      }
    }

    // epilogue: D mapping col=lane&15, row=(lane>>4)*4+v
    #pragma unroll
    for (int mt = 0; mt < MT; ++mt) {
      const int rowTop = base_m + mt*16 + ((lane >> 4) << 2);
      float lv[4] = {acc[mt].x + bv, acc[mt].y + bv, acc[mt].z + bv, acc[mt].w + bv};
      #pragma unroll
      for (int v = 0; v < 4; ++v) {
        int m = rowTop + v;
        if (m < nA && ws->targets[m*NG + g] == cl) ws->tLogit[m*NG + g] = lv[v];
      }
      float es[4], mv[4]; int mi[4];
      #pragma unroll
      for (int v = 0; v < 4; ++v) { es[v] = expf(lv[v]); mv[v] = lv[v]; mi[v] = cl; }
      #pragma unroll
      for (int off = 1; off < 16; off <<= 1) {
        #pragma unroll
        for (int v = 0; v < 4; ++v) {
          es[v] += __shfl_xor(es[v], off);
          float ov = __shfl_xor(mv[v], off);
          int   oi = __shfl_xor(mi[v], off);
          if (ov > mv[v] || (ov == mv[v] && oi < mi[v])) { mv[v] = ov; mi[v] = oi; }
        }
      }
      if ((lane & 15) == 0) {
        #pragma unroll
        for (int v = 0; v < 4; ++v) {
          int m = rowTop + v;
          if (m < nA) {
            atomicAdd(&ws->sumExp[m*NG + g], es[v]);
            unsigned key = __float_as_uint(mv[v]);
            key = (key & 0x80000000u) ? ~key : (key | 0x80000000u);
            unsigned long long pk = ((unsigned long long)key << 32)
                                  | (unsigned long long)(0xFFFFFFFFu - (unsigned)mi[v]);
            atomicMax(&ws->amax[m*NG + g], pk);
          }
        }
      }
    }
  }
}

// ======================= fallback fp32 path (round-1, proven) ==============
__global__ __launch_bounds__(256) void k_quant(
    const float* __restrict__ feats, const float* __restrict__ mean,
    const float* __restrict__ istd, const float* __restrict__ projw,
    const float* __restrict__ emb, Ws* ws) {
  if (blockIdx.x >= ws->nA) return;
  int ai = blockIdx.x;
  int p = ws->activeList[ai];
  int b = p >> 8, ts = p & (NTS-1);
  int tid = threadIdx.x;
  __shared__ float sN[SFD];
  __shared__ float sPart[4*64];
  __shared__ float sLat[NG*NE];
  __shared__ float sRedS[256];
  __shared__ int   sRedC[256];
  __shared__ float rS[4], rQ[4];
  __shared__ int   sTgt[NG];

  for (int j = tid; j < SFD; j += 256) {
    int k = j / NF, f = j - k*NF;
    sN[j] = (feats[((size_t)b*NT + ts*NSTRIDE + k)*NF + f] - mean[f]) * istd[f];
  }
  __syncthreads();
  float s = 0.f, q = 0.f;
  for (int j = tid; j < SFD; j += 256) { float x = sN[j]; s += x; q += x*x; }
  for (int o = 32; o; o >>= 1) { s += __shfl_down(s, o); q += __shfl_down(q, o); }
  if ((tid & 63) == 0) { rS[tid>>6] = s; rQ[tid>>6] = q; }
  __syncthreads();
  float mu  = (rS[0]+rS[1]+rS[2]+rS[3]) * (1.f/SFD);
  float var = (rQ[0]+rQ[1]+rQ[2]+rQ[3]) * (1.f/SFD) - mu*mu;
  float inv = rsqrtf(var + LNEPS);
  for (int j = tid; j < SFD; j += 256) sN[j] = (sN[j]-mu)*inv;
  __syncthreads();
  {
    int j = tid & 63, part = tid >> 6;
    float a = 0.f;
    int i0 = part*80;
    for (int i = i0; i < i0+80; ++i) a = fmaf(sN[i], projw[i*64 + j], a);
    sPart[part*64 + j] = a;
  }
  __syncthreads();
  if (tid < 64) sLat[tid] = sPart[tid] + sPart[64+tid] + sPart[128+tid] + sPart[192+tid];
  __syncthreads();

  for (int gg = 0; gg < NG; ++gg) {
    float lg[NE];
    #pragma unroll
    for (int e = 0; e < NE; ++e) lg[e] = sLat[gg*NE + e];
    float best = 3.4e38f; int bc = NC;
    for (int c = tid; c < NC; c += 256) {
      const float4* cb4 = reinterpret_cast<const float4*>(emb + ((size_t)c*NG + gg)*NE);
      float4 a0 = cb4[0], a1 = cb4[1], a2 = cb4[2], a3 = cb4[3];
      float dot = 0.f, n2 = 0.f;
      dot = fmaf(lg[0],  a0.x, dot); n2 = fmaf(a0.x, a0.x, n2);
      dot = fmaf(lg[1],  a0.y, dot); n2 = fmaf(a0.y, a0.y, n2);
      dot = fmaf(lg[2],  a0.z, dot); n2 = fmaf(a0.z, a0.z, n2);
      dot = fmaf(lg[3],  a0.w, dot); n2 = fmaf(a0.w, a0.w, n2);
      dot = fmaf(lg[4],  a1.x, dot); n2 = fmaf(a1.x, a1.x, n2);
      dot = fmaf(lg[5],  a1.y, dot); n2 = fmaf(a1.y, a1.y, n2);
      dot = fmaf(lg[6],  a1.z, dot); n2 = fmaf(a1.z, a1.z, n2);
      dot = fmaf(lg[7],  a1.w, dot); n2 = fmaf(a1.w, a1.w, n2);
      dot = fmaf(lg[8],  a2.x, dot); n2 = fmaf(a2.x, a2.x, n2);
      dot = fmaf(lg[9],  a2.y, dot); n2 = fmaf(a2.y, a2.y, n2);
      dot = fmaf(lg[10], a2.z, dot); n2 = fmaf(a2.z, a2.z, n2);
      dot = fmaf(lg[11], a2.w, dot); n2 = fmaf(a2.w, a2.w, n2);
      dot = fmaf(lg[12], a3.x, dot); n2 = fmaf(a3.x, a3.x, n2);
      dot = fmaf(lg[13], a3.y, dot); n2 = fmaf(a3.y, a3.y, n2);
      dot = fmaf(lg[14], a3.z, dot); n2 = fmaf(a3.z, a3.z, n2);
      dot = fmaf(lg[15], a3.w, dot); n2 = fmaf(a3.w, a3.w, n2);
      float sc = n2 - 2.f*dot;
      if (sc < best) { best = sc; bc = c; }
    }
    sRedS[tid] = best; sRedC[tid] = bc;
    __syncthreads();
    for (int off = 128; off; off >>= 1) {
      if (tid < off) {
        float os = sRedS[tid+off]; int oc = sRedC[tid+off];
        if (os < sRedS[tid] || (os == sRedS[tid] && oc < sRedC[tid])) {
          sRedS[tid] = os; sRedC[tid] = oc;
        }
      }
      __syncthreads();
    }
    if (tid == 0) sTgt[gg] = sRedC[0];
    __syncthreads();
  }
  if (tid < NG) {
    int c = sTgt[tid];
    ws->targets[ai*NG + tid] = c;
    atomicOr(&ws->bitmap[c >> 5], 1u << (c & 31));
  }
}

__global__ __launch_bounds__(256) void k_logits(
    const float* __restrict__ W, const float* __restrict__ bias,
    const float* __restrict__ enc, Ws* ws) {
  const int nA = (int)ws->nA;
  if (nA == 0) return;
  const int nCh = (nA + PCH - 1) / PCH;
  const int g = blockIdx.y;
  const int cbase = blockIdx.x * TCC + threadIdx.x * CPT;
  const float* __restrict__ Wg = W + (size_t)g*ND*NC;
  const float b0 = bias[g*NC + cbase + 0];
  const float b1 = bias[g*NC + cbase + 1];
  const float b2 = bias[g*NC + cbase + 2];
  const float b3 = bias[g*NC + cbase + 3];
  __shared__ float4 sEnc[PCH][ND/4];
  __shared__ int sP[PCH];

  for (int ch = blockIdx.z; ch < nCh; ch += PB) {
    if (threadIdx.x < PCH) {
      int ai = ch*PCH + threadIdx.x;
      sP[threadIdx.x] = (ai < nA) ? ws->activeList[ai] : -1;
    }
    __syncthreads();
    for (int i = threadIdx.x; i < PCH*(ND/4); i += 256) {
      int qq = i >> 7, r = i & 127;
      int p = sP[qq];
      sEnc[qq][r] = (p >= 0) ? reinterpret_cast<const float4*>(enc)[p*(ND/4) + r]
                             : make_float4(0.f, 0.f, 0.f, 0.f);
    }
    __syncthreads();

    float acc[PCH][CPT];
    #pragma unroll
    for (int qq = 0; qq < PCH; ++qq)
      #pragma unroll
      for (int j = 0; j < CPT; ++j) acc[qq][j] = 0.f;
    for (int d = 0; d < ND; d += 4) {
      const float* wp = Wg + (size_t)d*NC + cbase;
      float4 w0 = *reinterpret_cast<const float4*>(wp);
      float4 w1 = *reinterpret_cast<const float4*>(wp + NC);
      float4 w2 = *reinterpret_cast<const float4*>(wp + 2*NC);
      float4 w3 = *reinterpret_cast<const float4*>(wp + 3*NC);
      int dq = d >> 2;
      #pragma unroll
      for (int qq = 0; qq < PCH; ++qq) {
        float4 e = sEnc[qq][dq];
        acc[qq][0] = fmaf(e.x, w0.x, acc[qq][0]);
        acc[qq][1] = fmaf(e.x, w0.y, acc[qq][1]);
        acc[qq][2] = fmaf(e.x, w0.z, acc[qq][2]);
        acc[qq][3] = fmaf(e.x, w0.w, acc[qq][3]);
        acc[qq][0] = fmaf(e.y, w1.x, acc[qq][0]);
        acc[qq][1] = fmaf(e.y, w1.y, acc[qq][1]);
        acc[qq][2] = fmaf(e.y, w1.z, acc[qq][2]);
        acc[qq][3] = fmaf(e.y, w1.w, acc[qq][3]);
        acc[qq][0] = fmaf(e.z, w2.x, acc[qq][0]);
        acc[qq][1] = fmaf(e.z, w2.y, acc[qq][1]);
        acc[qq][2] = fmaf(e.z, w2.z, acc[qq][2]);
        acc[qq][3] = fmaf(e.z, w2.w, acc[qq][3]);
        acc[qq][0] = fmaf(e.w, w3.x, acc[qq][0]);
        acc[qq][1] = fmaf(e.w, w3.y, acc[qq][1]);
        acc[qq][2] = fmaf(e.w, w3.z, acc[qq][2]);
        acc[qq][3] = fmaf(e.w, w3.w, acc[qq][3]);
      }
    }

    #pragma unroll
    for (int qq = 0; qq < PCH; ++qq) {
      int ai = ch*PCH + qq;
      if (ai < nA) {
        float l0 = acc[qq][0] + b0;
        float l1 = acc[qq][1] + b1;
        float l2 = acc[qq][2] + b2;
        float l3 = acc[qq][3] + b3;
        int tgt = ws->targets[ai*NG + g];
        if ((unsigned)(tgt - cbase) < (unsigned)CPT) {
          float tv = (tgt == cbase) ? l0 : (tgt == cbase+1) ? l1
                   : (tgt == cbase+2) ? l2 : l3;
          ws->tLogit[ai*NG + g] = tv;
        }
        float es = expf(l0) + expf(l1) + expf(l2) + expf(l3);
        float mv = l0; int mi = cbase;
        if (l1 > mv) { mv = l1; mi = cbase+1; }
        if (l2 > mv) { mv = l2; mi = cbase+2; }
        if (l3 > mv) { mv = l3; mi = cbase+3; }
        for (int o = 32; o; o >>= 1) {
          es += __shfl_down(es, o);
          float ov = __shfl_down(mv, o);
          int   oi = __shfl_down(mi, o);
          if (ov > mv || (ov == mv && oi < mi)) { mv = ov; mi = oi; }
        }
        if ((threadIdx.x & 63) == 0) {
          atomicAdd(&ws->sumExp[ai*NG + g], es);
          unsigned key = __float_as_uint(mv);
          key = (key & 0x80000000u) ? ~key : (key | 0x80000000u);
          unsigned long long pk =
              ((unsigned long long)key << 32) |
              (unsigned long long)(0xFFFFFFFFu - (unsigned)mi);
          atomicMax(&ws->amax[ai*NG + g], pk);
        }
      }
    }
    __syncthreads();
  }
}
// ======================= end fallback =======================================

// ---- final scalar assembly ----
__global__ __launch_bounds__(256) void k_final(Ws* ws, float* __restrict__ out) {
  int tid = threadIdx.x;
  int nA = (int)ws->nA;
  float sumPer = 0.f, sumCorr = 0.f;
  for (int i = tid; i < nA*NG; i += 256) {
    sumPer += logf(ws->sumExp[i]) - ws->tLogit[i];
    unsigned long long pk = ws->amax[i];
    int mi = (int)(0xFFFFFFFFu - (unsigned)(pk & 0xFFFFFFFFull));
    if (mi == ws->targets[i]) sumCorr += 1.f;
  }
  unsigned w = ws->bitmap[tid];
  if (tid == 0 && nA < NP) w |= 1u;
  int uniq = __popc(w);

  __shared__ float rs[4], rc[4]; __shared__ int ru[4];
  float s1 = sumPer, s2 = sumCorr; int s3 = uniq;
  for (int o = 32; o; o >>= 1) {
    s1 += __shfl_down(s1, o);
    s2 += __shfl_down(s2, o);
    s3 += __shfl_down(s3, o);
  }
  if ((tid & 63) == 0) { rs[tid>>6] = s1; rc[tid>>6] = s2; ru[tid>>6] = s3; }
  __syncthreads();
  if (tid == 0) {
    float sp = rs[0]+rs[1]+rs[2]+rs[3];
    float sc = rc[0]+rc[1]+rc[2]+rc[3];
    int   un = ru[0]+ru[1]+ru[2]+ru[3];
    float pen   = ws->penSum / (float)(NB*NT*NF);
    float denom = (float)nA + 1e-5f;
    float nc    = (float)(nA * NG);
    out[0] = sp / (denom * (float)NG) + FREG * pen;
    out[1] = sc / nc;
    out[2] = pen;
    out[3] = nc;
    out[4] = (float)un;
  }
}

extern "C" void kernel_launch(void* const* d_in, const int* in_sizes, int n_in,
                              void* d_out, int out_size, void* d_ws, size_t ws_size,
                              hipStream_t stream) {
  const float* feats = (const float*)d_in[0];
  const int*   lens  = (const int*)d_in[1];
  const unsigned char* masks = (const unsigned char*)d_in[2];
  const float* mean  = (const float*)d_in[4];
  const float* istd  = (const float*)d_in[5];
  const float* projw = (const float*)d_in[6];
  const float* emb   = (const float*)d_in[7];
  const float* W     = (const float*)d_in[8];
  const float* bias  = (const float*)d_in[9];
  const float* enc   = (const float*)d_in[10];
  Ws* ws = (Ws*)d_ws;
  float* out = (float*)d_out;

  bool big = ws_size >= sizeof(Ws);
  size_t hdr = offsetof(Ws, lat);
  hipMemsetAsync(d_ws, 0, big ? hdr : (ws_size < hdr ? ws_size : hdr), stream);

  k_detect<<<1, 256, 0, stream>>>(masks, ws);
  k_pen<<<256, 256, 0, stream>>>(feats, mean, istd, ws);
  k_mask<<<NP/256, 256, 0, stream>>>(masks, lens, ws);

  if (big) {
    hipMemsetAsync(&ws->amin[0], 0xFF, sizeof(ws->amin), stream);
    k_latent<<<NP, 256, 0, stream>>>(feats, mean, istd, projw, ws);
    k_prepA<<<ROWS_MAX, 64, 0, stream>>>(enc, ws);
    k_qdist<<<dim3(NC/64, 2), 256, 0, stream>>>(emb, ws);
    k_tgt<<<NP*NG/256, 256, 0, stream>>>(ws);
    k_logits_mfma<<<dim3(NC/64, NG), 256, 0, stream>>>(W, bias, ws);
  } else {
    k_quant<<<NP, 256, 0, stream>>>(feats, mean, istd, projw, emb, ws);
    k_logits<<<dim3(NC/TCC, NG, PB), 256, 0, stream>>>(W, bias, enc, ws);
  }
  k_final<<<1, 256, 0, stream>>>(ws, out);
}

// Round 3
// 183.287 us; speedup vs baseline: 3.5706x; 3.5706x over previous
//
#include <hip/hip_runtime.h>
#include <hip/hip_bf16.h>
#include <math.h>
#include <stddef.h>

// Problem constants (from reference)
#define NB 8
#define NT 1024
#define NF 80
#define NSTACK 4
#define NSTRIDE 4
#define NG 4
#define NE 16
#define NC 8192
#define ND 512
#define NTS 256          // (NT-NSTACK)/NSTRIDE + 1
#define NP (NB*NTS)      // 2048 subsampled positions
#define SFD (NSTACK*NF)  // 320
#define FREG 0.01f
#define LNEPS 1e-5f

// fp32-fallback k_logits tiling
#define TCC 1024
#define CPT 4
#define PCH 16
#define PB 16

// MFMA path
#define ROWS_MAX 2176     // ceil(2048/144)*144 = 2160, padded
#define MT 9              // m-tiles per super-pass (144 rows)
#define QCH 128           // lat rows staged per k_qdist pass
#define CT 128            // c-tiles of 64 for the logits GEMM partials
#define QS 8              // qdist atomic spread slots

typedef __attribute__((ext_vector_type(8))) short short8;
typedef __attribute__((ext_vector_type(4))) float f32x4;

struct Ws {
  // ---------- zero-initialized region ----------
  float penSum;
  unsigned int nA;
  unsigned int maskIsInt;
  unsigned int pad1;
  unsigned long long amax[NP*NG];   // final packed (key<<32 | ~idx) argmax
  float sumExp[NP*NG];
  float tLogit[NP*NG];
  int   targets[NP*NG];
  int   activeList[NP];
  unsigned int bitmap[NC/32];
  // ---------- 0xFF-initialized region ----------
  unsigned long long aminS[NP*NG*QS]; // qdist spread argmin slots
  // ---------- no init needed ----------
  float lat[NP][64];
  unsigned short aHi[(size_t)ROWS_MAX*ND];
  unsigned short aLo[(size_t)ROWS_MAX*ND];
  float part_se[NG][ROWS_MAX][CT];
  unsigned long long part_mx[NG][ROWS_MAX][CT];
};

__device__ inline unsigned short bf16_rne(float x) {
  unsigned u = __float_as_uint(x);
  unsigned r = u + 0x7FFFu + ((u >> 16) & 1u);
  return (unsigned short)(r >> 16);
}
__device__ inline unsigned fkey_asc(float d) {  // ascending float -> ascending uint
  unsigned u = __float_as_uint(d);
  return (u & 0x80000000u) ? ~u : (u | 0x80000000u);
}

// ---- detect whether masks buffer is uint8 (numpy bool) or int32 ----
__global__ void k_detect(const unsigned char* __restrict__ m, Ws* ws) {
  __shared__ unsigned flag;
  if (threadIdx.x == 0) flag = 0;
  __syncthreads();
  unsigned nz = 0;
  int base = threadIdx.x * 32;
  for (int i = base; i < base + 32; ++i)
    if ((i & 3) && m[i]) nz = 1;
  if (nz) atomicOr(&flag, 1u);
  __syncthreads();
  if (threadIdx.x == 0) ws->maskIsInt = (flag ? 0u : 1u);
}

// ---- features_pen ----
__global__ void k_pen(const float* __restrict__ feats,
                      const float* __restrict__ mean,
                      const float* __restrict__ istd, Ws* ws) {
  const int N4 = NB*NT*NF/4;
  float s = 0.f;
  for (int i = blockIdx.x*blockDim.x + threadIdx.x; i < N4; i += gridDim.x*blockDim.x) {
    float4 v = reinterpret_cast<const float4*>(feats)[i];
    int f0 = (i*4) % NF;
    float x0 = (v.x - mean[f0+0]) * istd[f0+0];
    float x1 = (v.y - mean[f0+1]) * istd[f0+1];
    float x2 = (v.z - mean[f0+2]) * istd[f0+2];
    float x3 = (v.w - mean[f0+3]) * istd[f0+3];
    s += x0*x0 + x1*x1 + x2*x2 + x3*x3;
  }
  for (int o = 32; o; o >>= 1) s += __shfl_down(s, o);
  __shared__ float pr[4];
  if ((threadIdx.x & 63) == 0) pr[threadIdx.x >> 6] = s;
  __syncthreads();
  if (threadIdx.x == 0) atomicAdd(&ws->penSum, pr[0]+pr[1]+pr[2]+pr[3]);
}

// ---- mask + compact ----
__global__ void k_mask(const unsigned char* __restrict__ m8,
                       const int* __restrict__ lens, Ws* ws) {
  int p = blockIdx.x*blockDim.x + threadIdx.x;
  if (p >= NP) return;
  int b = p >> 8, ts = p & (NTS-1);
  int t0 = b*NT + ts*NSTRIDE;
  bool allm;
  if (ws->maskIsInt) {
    const int* m32 = (const int*)m8;
    allm = m32[t0] && m32[t0+1] && m32[t0+2] && m32[t0+3];
  } else {
    allm = m8[t0] && m8[t0+1] && m8[t0+2] && m8[t0+3];
  }
  int ls = (lens[b] - NSTACK)/NSTRIDE + 1;
  if (ls < 0) ls = 0;
  if (allm && ts < ls) {
    unsigned idx = atomicAdd(&ws->nA, 1u);
    ws->activeList[idx] = p;
  }
}

// ---- latents: stack + LayerNorm + projection -> ws->lat[ai][64] ----
__global__ __launch_bounds__(256) void k_latent(
    const float* __restrict__ feats, const float* __restrict__ mean,
    const float* __restrict__ istd, const float* __restrict__ projw, Ws* ws) {
  if (blockIdx.x >= ws->nA) return;
  int ai = blockIdx.x;
  int p = ws->activeList[ai];
  int b = p >> 8, ts = p & (NTS-1);
  int tid = threadIdx.x;
  __shared__ float sN[SFD];
  __shared__ float sPart[4*64];
  __shared__ float rS[4], rQ[4];

  for (int j = tid; j < SFD; j += 256) {
    int k = j / NF, f = j - k*NF;
    sN[j] = (feats[((size_t)b*NT + ts*NSTRIDE + k)*NF + f] - mean[f]) * istd[f];
  }
  __syncthreads();
  float s = 0.f, q = 0.f;
  for (int j = tid; j < SFD; j += 256) { float x = sN[j]; s += x; q += x*x; }
  for (int o = 32; o; o >>= 1) { s += __shfl_down(s, o); q += __shfl_down(q, o); }
  if ((tid & 63) == 0) { rS[tid>>6] = s; rQ[tid>>6] = q; }
  __syncthreads();
  float mu  = (rS[0]+rS[1]+rS[2]+rS[3]) * (1.f/SFD);
  float var = (rQ[0]+rQ[1]+rQ[2]+rQ[3]) * (1.f/SFD) - mu*mu;
  float inv = rsqrtf(var + LNEPS);
  for (int j = tid; j < SFD; j += 256) sN[j] = (sN[j]-mu)*inv;
  __syncthreads();
  {
    int j = tid & 63, part = tid >> 6;
    float a = 0.f;
    int i0 = part*80;
    for (int i = i0; i < i0+80; ++i) a = fmaf(sN[i], projw[i*64 + j], a);
    sPart[part*64 + j] = a;
  }
  __syncthreads();
  if (tid < 64)
    ws->lat[ai][tid] = sPart[tid] + sPart[64+tid] + sPart[128+tid] + sPart[192+tid];
}

// ---- codebook argmin, c-parallel; spread atomicMin (8 slots) ----
__global__ __launch_bounds__(256) void k_qdist(const float* __restrict__ emb, Ws* ws) {
  int nA = (int)ws->nA;
  if (nA == 0) return;
  int tid = threadIdx.x;
  int g = tid >> 6, lane = tid & 63;
  int c = blockIdx.x * 64 + lane;
  int per = (nA + 1) >> 1;
  int a0 = blockIdx.y * per;
  int a1 = min(nA, a0 + per);
  int slot = blockIdx.x & (QS-1);

  const float4* e4 = reinterpret_cast<const float4*>(emb + ((size_t)c*NG + g)*NE);
  float4 b0 = e4[0], b1 = e4[1], b2 = e4[2], b3 = e4[3];
  float n2 = b0.x*b0.x + b0.y*b0.y + b0.z*b0.z + b0.w*b0.w
           + b1.x*b1.x + b1.y*b1.y + b1.z*b1.z + b1.w*b1.w
           + b2.x*b2.x + b2.y*b2.y + b2.z*b2.z + b2.w*b2.w
           + b3.x*b3.x + b3.y*b3.y + b3.z*b3.z + b3.w*b3.w;

  __shared__ float sL[QCH][64];
  for (int base = a0; base < a1; base += QCH) {
    int cnt = min(QCH, a1 - base);
    __syncthreads();
    for (int i = tid; i < cnt*64; i += 256)
      (&sL[0][0])[i] = (&ws->lat[0][0])[(size_t)(base + (i >> 6))*64 + (i & 63)];
    __syncthreads();
    for (int i = 0; i < cnt; ++i) {
      const float* lp = &sL[i][g*NE];
      float dot = lp[0]*b0.x + lp[1]*b0.y + lp[2]*b0.z + lp[3]*b0.w
                + lp[4]*b1.x + lp[5]*b1.y + lp[6]*b1.z + lp[7]*b1.w
                + lp[8]*b2.x + lp[9]*b2.y + lp[10]*b2.z + lp[11]*b2.w
                + lp[12]*b3.x + lp[13]*b3.y + lp[14]*b3.z + lp[15]*b3.w;
      float d = n2 - 2.f*dot;
      float mv = d; int mc = c;
      #pragma unroll
      for (int off = 32; off; off >>= 1) {
        float ov = __shfl_xor(mv, off);
        int   oc = __shfl_xor(mc, off);
        if (ov < mv || (ov == mv && oc < mc)) { mv = ov; mc = oc; }
      }
      if (lane == 0) {
        unsigned long long key =
            ((unsigned long long)fkey_asc(mv) << 32) | (unsigned)mc;
        atomicMin(&ws->aminS[(size_t)((base + i)*NG + g)*QS + slot], key);
      }
    }
  }
}

// ---- extract targets + uniq bitmap from spread slots ----
__global__ void k_tgt(Ws* ws) {
  int i = blockIdx.x*256 + threadIdx.x;
  int nA = (int)ws->nA;
  if (i < nA*NG) {
    unsigned long long m = ws->aminS[(size_t)i*QS];
    #pragma unroll
    for (int s = 1; s < QS; ++s) {
      unsigned long long v = ws->aminS[(size_t)i*QS + s];
      if (v < m) m = v;
    }
    int c = (int)(unsigned)(m & 0xFFFFFFFFull);
    ws->targets[i] = c;
    atomicOr(&ws->bitmap[c >> 5], 1u << (c & 31));
  }
}

// ---- precompute bf16 hi/lo splits of active encoder rows (zero-padded) ----
__global__ void k_prepA(const float* __restrict__ enc, Ws* ws) {
  int ai = blockIdx.x;
  int nA = (int)ws->nA;
  int limit = ((nA + (MT*16 - 1)) / (MT*16)) * (MT*16);
  if (ai >= limit) return;
  int lane = threadIdx.x;  // 64 threads
  const float* src = (ai < nA) ? enc + (size_t)ws->activeList[ai]*ND : nullptr;
  for (int t = 0; t < ND/64; ++t) {
    int d = t*64 + lane;
    float x = (ai < nA) ? src[d] : 0.f;
    unsigned short hi = bf16_rne(x);
    float rem = x - __uint_as_float((unsigned)hi << 16);
    unsigned short lo = bf16_rne(rem);
    ws->aHi[(size_t)ai*ND + d] = hi;
    ws->aLo[(size_t)ai*ND + d] = lo;
  }
}

// ---- logits GEMM: LDS-staged W, MFMA bf16 3-product, atomic-free epilogue ----
__global__ __launch_bounds__(256) void k_logits_mfma(
    const float* __restrict__ W, const float* __restrict__ bias, Ws* ws) {
  const int nA = (int)ws->nA;
  if (nA == 0) return;
  const int nSup = (nA + (MT*16 - 1)) / (MT*16);
  const int tid = threadIdx.x;
  const int wave = tid >> 6, lane = tid & 63;
  const int g = blockIdx.y;
  const int c0 = blockIdx.x * 64;
  const int cl_local = wave*16 + (lane & 15);
  const int cl = c0 + cl_local;
  const int klane = (lane >> 4) * 8;
  const float bv = bias[g*NC + cl];

  __shared__ float sW[64][65];              // 64k x 64c tile, pad-65
  __shared__ float sEs[4][MT*16];
  __shared__ unsigned long long sMx[4][MT*16];

  for (int sup = 0; sup < nSup; ++sup) {
    const int base_m = sup * (MT*16);
    f32x4 acc[MT];
    #pragma unroll
    for (int mt = 0; mt < MT; ++mt) acc[mt] = (f32x4){0.f, 0.f, 0.f, 0.f};

    for (int kt = 0; kt < ND/64; ++kt) {
      __syncthreads();
      {
        const float* gp = W + ((size_t)g*ND + kt*64)*NC + c0;
        #pragma unroll
        for (int it = 0; it < 4; ++it) {
          int idx = it*256 + tid;
          int r = idx >> 4, cc = (idx & 15) * 4;
          float4 v = *reinterpret_cast<const float4*>(gp + (size_t)r*NC + cc);
          sW[r][cc]   = v.x; sW[r][cc+1] = v.y;
          sW[r][cc+2] = v.z; sW[r][cc+3] = v.w;
        }
      }
      __syncthreads();

      #pragma unroll
      for (int ki = 0; ki < 2; ++ki) {
        const int klo = ki*32 + klane;
        float wv[8];
        #pragma unroll
        for (int j = 0; j < 8; ++j) wv[j] = sW[klo + j][cl_local];
        short8 whi, wlo;
        #pragma unroll
        for (int j = 0; j < 8; ++j) {
          unsigned short h = bf16_rne(wv[j]);
          float rem = wv[j] - __uint_as_float((unsigned)h << 16);
          whi[j] = (short)h;
          wlo[j] = (short)bf16_rne(rem);
        }
        const size_t aoff = (size_t)(base_m + (lane & 15))*ND + kt*64 + ki*32 + klane;
        #pragma unroll
        for (int mt = 0; mt < MT; ++mt) {
          short8 ahi = *reinterpret_cast<const short8*>(ws->aHi + aoff + (size_t)mt*16*ND);
          short8 alo = *reinterpret_cast<const short8*>(ws->aLo + aoff + (size_t)mt*16*ND);
          acc[mt] = __builtin_amdgcn_mfma_f32_16x16x32_bf16(ahi, whi, acc[mt], 0, 0, 0);
          acc[mt] = __builtin_amdgcn_mfma_f32_16x16x32_bf16(ahi, wlo, acc[mt], 0, 0, 0);
          acc[mt] = __builtin_amdgcn_mfma_f32_16x16x32_bf16(alo, whi, acc[mt], 0, 0, 0);
        }
      }
    }

    // epilogue: per-wave 16-col reduction, then per-block LDS combine, plain stores
    #pragma unroll
    for (int mt = 0; mt < MT; ++mt) {
      const int rowTop = base_m + mt*16 + ((lane >> 4) << 2);
      float lv[4] = {acc[mt].x + bv, acc[mt].y + bv, acc[mt].z + bv, acc[mt].w + bv};
      #pragma unroll
      for (int v = 0; v < 4; ++v) {
        int m = rowTop + v;
        if (m < nA && ws->targets[m*NG + g] == cl) ws->tLogit[m*NG + g] = lv[v];
      }
      float es[4], mv[4]; int mi[4];
      #pragma unroll
      for (int v = 0; v < 4; ++v) { es[v] = expf(lv[v]); mv[v] = lv[v]; mi[v] = cl; }
      #pragma unroll
      for (int off = 1; off < 16; off <<= 1) {
        #pragma unroll
        for (int v = 0; v < 4; ++v) {
          es[v] += __shfl_xor(es[v], off);
          float ov = __shfl_xor(mv[v], off);
          int   oi = __shfl_xor(mi[v], off);
          if (ov > mv[v] || (ov == mv[v] && oi < mi[v])) { mv[v] = ov; mi[v] = oi; }
        }
      }
      if ((lane & 15) == 0) {
        int lr = mt*16 + ((lane >> 4) << 2);
        #pragma unroll
        for (int v = 0; v < 4; ++v) {
          sEs[wave][lr + v] = es[v];
          unsigned key = __float_as_uint(mv[v]);
          key = (key & 0x80000000u) ? ~key : (key | 0x80000000u);
          sMx[wave][lr + v] = ((unsigned long long)key << 32)
                            | (unsigned long long)(0xFFFFFFFFu - (unsigned)mi[v]);
        }
      }
    }
    __syncthreads();
    if (tid < MT*16) {
      float e = sEs[0][tid] + sEs[1][tid] + sEs[2][tid] + sEs[3][tid];
      unsigned long long m0 = sMx[0][tid], m1 = sMx[1][tid];
      unsigned long long m2 = sMx[2][tid], m3 = sMx[3][tid];
      unsigned long long ma = m0 > m1 ? m0 : m1;
      unsigned long long mb = m2 > m3 ? m2 : m3;
      unsigned long long mx = ma > mb ? ma : mb;
      int grow = base_m + tid;
      ws->part_se[g][grow][blockIdx.x] = e;
      ws->part_mx[g][grow][blockIdx.x] = mx;
    }
  }
}

// ---- reduce 128 c-tile partials per (row,g): plain stores, no atomics ----
__global__ __launch_bounds__(256) void k_red_l(Ws* ws) {
  int nA = (int)ws->nA;
  int pair = blockIdx.x*4 + (threadIdx.x >> 6);
  int lane = threadIdx.x & 63;
  int row = pair >> 2, g = pair & 3;
  if (row >= nA) return;
  float e = ws->part_se[g][row][lane] + ws->part_se[g][row][lane + 64];
  unsigned long long a = ws->part_mx[g][row][lane];
  unsigned long long b = ws->part_mx[g][row][lane + 64];
  unsigned long long mx = a > b ? a : b;
  #pragma unroll
  for (int off = 32; off; off >>= 1) {
    e += __shfl_xor(e, off);
    unsigned long long o = __shfl_xor(mx, off);
    if (o > mx) mx = o;
  }
  if (lane == 0) {
    ws->sumExp[row*NG + g] = e;
    ws->amax[row*NG + g] = mx;
  }
}

// ======================= fallback fp32 path (round-1, proven) ==============
__global__ __launch_bounds__(256) void k_quant(
    const float* __restrict__ feats, const float* __restrict__ mean,
    const float* __restrict__ istd, const float* __restrict__ projw,
    const float* __restrict__ emb, Ws* ws) {
  if (blockIdx.x >= ws->nA) return;
  int ai = blockIdx.x;
  int p = ws->activeList[ai];
  int b = p >> 8, ts = p & (NTS-1);
  int tid = threadIdx.x;
  __shared__ float sN[SFD];
  __shared__ float sPart[4*64];
  __shared__ float sLat[NG*NE];
  __shared__ float sRedS[256];
  __shared__ int   sRedC[256];
  __shared__ float rS[4], rQ[4];
  __shared__ int   sTgt[NG];

  for (int j = tid; j < SFD; j += 256) {
    int k = j / NF, f = j - k*NF;
    sN[j] = (feats[((size_t)b*NT + ts*NSTRIDE + k)*NF + f] - mean[f]) * istd[f];
  }
  __syncthreads();
  float s = 0.f, q = 0.f;
  for (int j = tid; j < SFD; j += 256) { float x = sN[j]; s += x; q += x*x; }
  for (int o = 32; o; o >>= 1) { s += __shfl_down(s, o); q += __shfl_down(q, o); }
  if ((tid & 63) == 0) { rS[tid>>6] = s; rQ[tid>>6] = q; }
  __syncthreads();
  float mu  = (rS[0]+rS[1]+rS[2]+rS[3]) * (1.f/SFD);
  float var = (rQ[0]+rQ[1]+rQ[2]+rQ[3]) * (1.f/SFD) - mu*mu;
  float inv = rsqrtf(var + LNEPS);
  for (int j = tid; j < SFD; j += 256) sN[j] = (sN[j]-mu)*inv;
  __syncthreads();
  {
    int j = tid & 63, part = tid >> 6;
    float a = 0.f;
    int i0 = part*80;
    for (int i = i0; i < i0+80; ++i) a = fmaf(sN[i], projw[i*64 + j], a);
    sPart[part*64 + j] = a;
  }
  __syncthreads();
  if (tid < 64) sLat[tid] = sPart[tid] + sPart[64+tid] + sPart[128+tid] + sPart[192+tid];
  __syncthreads();

  for (int gg = 0; gg < NG; ++gg) {
    float lg[NE];
    #pragma unroll
    for (int e = 0; e < NE; ++e) lg[e] = sLat[gg*NE + e];
    float best = 3.4e38f; int bc = NC;
    for (int c = tid; c < NC; c += 256) {
      const float4* cb4 = reinterpret_cast<const float4*>(emb + ((size_t)c*NG + gg)*NE);
      float4 a0 = cb4[0], a1 = cb4[1], a2 = cb4[2], a3 = cb4[3];
      float dot = 0.f, n2 = 0.f;
      dot = fmaf(lg[0],  a0.x, dot); n2 = fmaf(a0.x, a0.x, n2);
      dot = fmaf(lg[1],  a0.y, dot); n2 = fmaf(a0.y, a0.y, n2);
      dot = fmaf(lg[2],  a0.z, dot); n2 = fmaf(a0.z, a0.z, n2);
      dot = fmaf(lg[3],  a0.w, dot); n2 = fmaf(a0.w, a0.w, n2);
      dot = fmaf(lg[4],  a1.x, dot); n2 = fmaf(a1.x, a1.x, n2);
      dot = fmaf(lg[5],  a1.y, dot); n2 = fmaf(a1.y, a1.y, n2);
      dot = fmaf(lg[6],  a1.z, dot); n2 = fmaf(a1.z, a1.z, n2);
      dot = fmaf(lg[7],  a1.w, dot); n2 = fmaf(a1.w, a1.w, n2);
      dot = fmaf(lg[8],  a2.x, dot); n2 = fmaf(a2.x, a2.x, n2);
      dot = fmaf(lg[9],  a2.y, dot); n2 = fmaf(a2.y, a2.y, n2);
      dot = fmaf(lg[10], a2.z, dot); n2 = fmaf(a2.z, a2.z, n2);
      dot = fmaf(lg[11], a2.w, dot); n2 = fmaf(a2.w, a2.w, n2);
      dot = fmaf(lg[12], a3.x, dot); n2 = fmaf(a3.x, a3.x, n2);
      dot = fmaf(lg[13], a3.y, dot); n2 = fmaf(a3.y, a3.y, n2);
      dot = fmaf(lg[14], a3.z, dot); n2 = fmaf(a3.z, a3.z, n2);
      dot = fmaf(lg[15], a3.w, dot); n2 = fmaf(a3.w, a3.w, n2);
      float sc = n2 - 2.f*dot;
      if (sc < best) { best = sc; bc = c; }
    }
    sRedS[tid] = best; sRedC[tid] = bc;
    __syncthreads();
    for (int off = 128; off; off >>= 1) {
      if (tid < off) {
        float os = sRedS[tid+off]; int oc = sRedC[tid+off];
        if (os < sRedS[tid] || (os == sRedS[tid] && oc < sRedC[tid])) {
          sRedS[tid] = os; sRedC[tid] = oc;
        }
      }
      __syncthreads();
    }
    if (tid == 0) sTgt[gg] = sRedC[0];
    __syncthreads();
  }
  if (tid < NG) {
    int c = sTgt[tid];
    ws->targets[ai*NG + tid] = c;
    atomicOr(&ws->bitmap[c >> 5], 1u << (c & 31));
  }
}

__global__ __launch_bounds__(256) void k_logits(
    const float* __restrict__ W, const float* __restrict__ bias,
    const float* __restrict__ enc, Ws* ws) {
  const int nA = (int)ws->nA;
  if (nA == 0) return;
  const int nCh = (nA + PCH - 1) / PCH;
  const int g = blockIdx.y;
  const int cbase = blockIdx.x * TCC + threadIdx.x * CPT;
  const float* __restrict__ Wg = W + (size_t)g*ND*NC;
  const float b0 = bias[g*NC + cbase + 0];
  const float b1 = bias[g*NC + cbase + 1];
  const float b2 = bias[g*NC + cbase + 2];
  const float b3 = bias[g*NC + cbase + 3];
  __shared__ float4 sEnc[PCH][ND/4];
  __shared__ int sP[PCH];

  for (int ch = blockIdx.z; ch < nCh; ch += PB) {
    if (threadIdx.x < PCH) {
      int ai = ch*PCH + threadIdx.x;
      sP[threadIdx.x] = (ai < nA) ? ws->activeList[ai] : -1;
    }
    __syncthreads();
    for (int i = threadIdx.x; i < PCH*(ND/4); i += 256) {
      int qq = i >> 7, r = i & 127;
      int p = sP[qq];
      sEnc[qq][r] = (p >= 0) ? reinterpret_cast<const float4*>(enc)[p*(ND/4) + r]
                             : make_float4(0.f, 0.f, 0.f, 0.f);
    }
    __syncthreads();

    float acc[PCH][CPT];
    #pragma unroll
    for (int qq = 0; qq < PCH; ++qq)
      #pragma unroll
      for (int j = 0; j < CPT; ++j) acc[qq][j] = 0.f;
    for (int d = 0; d < ND; d += 4) {
      const float* wp = Wg + (size_t)d*NC + cbase;
      float4 w0 = *reinterpret_cast<const float4*>(wp);
      float4 w1 = *reinterpret_cast<const float4*>(wp + NC);
      float4 w2 = *reinterpret_cast<const float4*>(wp + 2*NC);
      float4 w3 = *reinterpret_cast<const float4*>(wp + 3*NC);
      int dq = d >> 2;
      #pragma unroll
      for (int qq = 0; qq < PCH; ++qq) {
        float4 e = sEnc[qq][dq];
        acc[qq][0] = fmaf(e.x, w0.x, acc[qq][0]);
        acc[qq][1] = fmaf(e.x, w0.y, acc[qq][1]);
        acc[qq][2] = fmaf(e.x, w0.z, acc[qq][2]);
        acc[qq][3] = fmaf(e.x, w0.w, acc[qq][3]);
        acc[qq][0] = fmaf(e.y, w1.x, acc[qq][0]);
        acc[qq][1] = fmaf(e.y, w1.y, acc[qq][1]);
        acc[qq][2] = fmaf(e.y, w1.z, acc[qq][2]);
        acc[qq][3] = fmaf(e.y, w1.w, acc[qq][3]);
        acc[qq][0] = fmaf(e.z, w2.x, acc[qq][0]);
        acc[qq][1] = fmaf(e.z, w2.y, acc[qq][1]);
        acc[qq][2] = fmaf(e.z, w2.z, acc[qq][2]);
        acc[qq][3] = fmaf(e.z, w2.w, acc[qq][3]);
        acc[qq][0] = fmaf(e.w, w3.x, acc[qq][0]);
        acc[qq][1] = fmaf(e.w, w3.y, acc[qq][1]);
        acc[qq][2] = fmaf(e.w, w3.z, acc[qq][2]);
        acc[qq][3] = fmaf(e.w, w3.w, acc[qq][3]);
      }
    }

    #pragma unroll
    for (int qq = 0; qq < PCH; ++qq) {
      int ai = ch*PCH + qq;
      if (ai < nA) {
        float l0 = acc[qq][0] + b0;
        float l1 = acc[qq][1] + b1;
        float l2 = acc[qq][2] + b2;
        float l3 = acc[qq][3] + b3;
        int tgt = ws->targets[ai*NG + g];
        if ((unsigned)(tgt - cbase) < (unsigned)CPT) {
          float tv = (tgt == cbase) ? l0 : (tgt == cbase+1) ? l1
                   : (tgt == cbase+2) ? l2 : l3;
          ws->tLogit[ai*NG + g] = tv;
        }
        float es = expf(l0) + expf(l1) + expf(l2) + expf(l3);
        float mv = l0; int mi = cbase;
        if (l1 > mv) { mv = l1; mi = cbase+1; }
        if (l2 > mv) { mv = l2; mi = cbase+2; }
        if (l3 > mv) { mv = l3; mi = cbase+3; }
        for (int o = 32; o; o >>= 1) {
          es += __shfl_down(es, o);
          float ov = __shfl_down(mv, o);
          int   oi = __shfl_down(mi, o);
          if (ov > mv || (ov == mv && oi < mi)) { mv = ov; mi = oi; }
        }
        if ((threadIdx.x & 63) == 0) {
          atomicAdd(&ws->sumExp[ai*NG + g], es);
          unsigned key = __float_as_uint(mv);
          key = (key & 0x80000000u) ? ~key : (key | 0x80000000u);
          unsigned long long pk =
              ((unsigned long long)key << 32) |
              (unsigned long long)(0xFFFFFFFFu - (unsigned)mi);
          atomicMax(&ws->amax[ai*NG + g], pk);
        }
      }
    }
    __syncthreads();
  }
}
// ======================= end fallback =======================================

// ---- final scalar assembly ----
__global__ __launch_bounds__(256) void k_final(Ws* ws, float* __restrict__ out) {
  int tid = threadIdx.x;
  int nA = (int)ws->nA;
  float sumPer = 0.f, sumCorr = 0.f;
  for (int i = tid; i < nA*NG; i += 256) {
    sumPer += logf(ws->sumExp[i]) - ws->tLogit[i];
    unsigned long long pk = ws->amax[i];
    int mi = (int)(0xFFFFFFFFu - (unsigned)(pk & 0xFFFFFFFFull));
    if (mi == ws->targets[i]) sumCorr += 1.f;
  }
  unsigned w = ws->bitmap[tid];
  if (tid == 0 && nA < NP) w |= 1u;
  int uniq = __popc(w);

  __shared__ float rs[4], rc[4]; __shared__ int ru[4];
  float s1 = sumPer, s2 = sumCorr; int s3 = uniq;
  for (int o = 32; o; o >>= 1) {
    s1 += __shfl_down(s1, o);
    s2 += __shfl_down(s2, o);
    s3 += __shfl_down(s3, o);
  }
  if ((tid & 63) == 0) { rs[tid>>6] = s1; rc[tid>>6] = s2; ru[tid>>6] = s3; }
  __syncthreads();
  if (tid == 0) {
    float sp = rs[0]+rs[1]+rs[2]+rs[3];
    float sc = rc[0]+rc[1]+rc[2]+rc[3];
    int   un = ru[0]+ru[1]+ru[2]+ru[3];
    float pen   = ws->penSum / (float)(NB*NT*NF);
    float denom = (float)nA + 1e-5f;
    float nc    = (float)(nA * NG);
    out[0] = sp / (denom * (float)NG) + FREG * pen;
    out[1] = sc / nc;
    out[2] = pen;
    out[3] = nc;
    out[4] = (float)un;
  }
}

extern "C" void kernel_launch(void* const* d_in, const int* in_sizes, int n_in,
                              void* d_out, int out_size, void* d_ws, size_t ws_size,
                              hipStream_t stream) {
  const float* feats = (const float*)d_in[0];
  const int*   lens  = (const int*)d_in[1];
  const unsigned char* masks = (const unsigned char*)d_in[2];
  const float* mean  = (const float*)d_in[4];
  const float* istd  = (const float*)d_in[5];
  const float* projw = (const float*)d_in[6];
  const float* emb   = (const float*)d_in[7];
  const float* W     = (const float*)d_in[8];
  const float* bias  = (const float*)d_in[9];
  const float* enc   = (const float*)d_in[10];
  Ws* ws = (Ws*)d_ws;
  float* out = (float*)d_out;

  bool big = ws_size >= sizeof(Ws);
  size_t zr = offsetof(Ws, aminS);
  hipMemsetAsync(d_ws, 0, (big || ws_size >= zr) ? zr : ws_size, stream);

  k_detect<<<1, 256, 0, stream>>>(masks, ws);
  k_pen<<<256, 256, 0, stream>>>(feats, mean, istd, ws);
  k_mask<<<NP/256, 256, 0, stream>>>(masks, lens, ws);

  if (big) {
    hipMemsetAsync(&ws->aminS[0], 0xFF, sizeof(ws->aminS), stream);
    k_latent<<<NP, 256, 0, stream>>>(feats, mean, istd, projw, ws);
    k_prepA<<<ROWS_MAX, 64, 0, stream>>>(enc, ws);
    k_qdist<<<dim3(NC/64, 2), 256, 0, stream>>>(emb, ws);
    k_tgt<<<NP*NG/256, 256, 0, stream>>>(ws);
    k_logits_mfma<<<dim3(CT, NG), 256, 0, stream>>>(W, bias, ws);
    k_red_l<<<NP, 256, 0, stream>>>(ws);
  } else {
    k_quant<<<NP, 256, 0, stream>>>(feats, mean, istd, projw, emb, ws);
    k_logits<<<dim3(NC/TCC, NG, PB), 256, 0, stream>>>(W, bias, enc, ws);
  }
  k_final<<<1, 256, 0, stream>>>(ws, out);
}

// Round 4
// 125.546 us; speedup vs baseline: 5.2128x; 1.4599x over previous
//
#include <hip/hip_runtime.h>
#include <hip/hip_bf16.h>
#include <math.h>
#include <stddef.h>

// Problem constants (from reference)
#define NB 8
#define NT 1024
#define NF 80
#define NSTACK 4
#define NSTRIDE 4
#define NG 4
#define NE 16
#define NC 8192
#define ND 512
#define NTS 256          // (NT-NSTACK)/NSTRIDE + 1
#define NP (NB*NTS)      // 2048 subsampled positions
#define SFD (NSTACK*NF)  // 320
#define FREG 0.01f
#define LNEPS 1e-5f

// fp32-fallback k_logits tiling
#define TCC 1024
#define CPT 4
#define PCH 16
#define PB 16

// MFMA path
#define ROWS_MAX 2176     // ceil(2048/144)*144 = 2160, padded
#define MT 9              // m-tiles (rows) held in acc regs (144 rows)
#define QCH 128           // lat rows staged per k_qdist pass
#define CT 128            // c-tiles of 64 for the logits GEMM partials
#define QS 8              // qdist atomic spread slots

typedef __attribute__((ext_vector_type(8))) short short8;
typedef __attribute__((ext_vector_type(4))) float f32x4;

struct Ws {
  // ---------- zero-initialized region ----------
  float penSum;
  unsigned int nA;
  unsigned int maskIsInt;
  unsigned int pad1;
  unsigned long long amax[NP*NG];   // final packed (key<<32 | ~idx) argmax
  float sumExp[NP*NG];
  float tLogit[NP*NG];
  int   targets[NP*NG];
  int   activeList[NP];
  unsigned int bitmap[NC/32];
  // ---------- 0xFF-initialized region ----------
  unsigned long long aminS[NP*NG*QS]; // qdist spread argmin slots
  // ---------- no init needed ----------
  float lat[NP][64];
  // fragment-order bf16 splits of active encoder rows:
  // aHiT[(k/8)*ROWS_MAX + row]*8 + (k%8)
  unsigned short aHiT[(size_t)(ND/8)*ROWS_MAX*8];
  unsigned short aLoT[(size_t)(ND/8)*ROWS_MAX*8];
  float part_se[NG][ROWS_MAX][CT];
  unsigned long long part_mx[NG][ROWS_MAX][CT];
};

__device__ inline unsigned short bf16_rne(float x) {
  unsigned u = __float_as_uint(x);
  unsigned r = u + 0x7FFFu + ((u >> 16) & 1u);
  return (unsigned short)(r >> 16);
}
__device__ inline unsigned fkey_asc(float d) {  // ascending float -> ascending uint
  unsigned u = __float_as_uint(d);
  return (u & 0x80000000u) ? ~u : (u | 0x80000000u);
}

// ---- features_pen ----
__global__ void k_pen(const float* __restrict__ feats,
                      const float* __restrict__ mean,
                      const float* __restrict__ istd, Ws* ws) {
  const int N4 = NB*NT*NF/4;
  float s = 0.f;
  for (int i = blockIdx.x*blockDim.x + threadIdx.x; i < N4; i += gridDim.x*blockDim.x) {
    float4 v = reinterpret_cast<const float4*>(feats)[i];
    int f0 = (i*4) % NF;
    float x0 = (v.x - mean[f0+0]) * istd[f0+0];
    float x1 = (v.y - mean[f0+1]) * istd[f0+1];
    float x2 = (v.z - mean[f0+2]) * istd[f0+2];
    float x3 = (v.w - mean[f0+3]) * istd[f0+3];
    s += x0*x0 + x1*x1 + x2*x2 + x3*x3;
  }
  for (int o = 32; o; o >>= 1) s += __shfl_down(s, o);
  __shared__ float pr[4];
  if ((threadIdx.x & 63) == 0) pr[threadIdx.x >> 6] = s;
  __syncthreads();
  if (threadIdx.x == 0) atomicAdd(&ws->penSum, pr[0]+pr[1]+pr[2]+pr[3]);
}

// ---- mask + compact (self-detecting uint8-vs-int32 mask layout) ----
// int32-encoded 0/1 bools have all bytes at offset%4!=0 equal to zero within
// the first 8192 bytes (valid read under both layouts); uint8 masks do not.
__global__ void k_mask(const unsigned char* __restrict__ m8,
                       const int* __restrict__ lens, Ws* ws) {
  __shared__ unsigned flag;
  if (threadIdx.x == 0) flag = 0;
  __syncthreads();
  unsigned nz = 0;
  int base = threadIdx.x * 32;
  for (int i = base; i < base + 32; ++i)
    if ((i & 3) && m8[i]) nz = 1;
  if (nz) atomicOr(&flag, 1u);
  __syncthreads();
  bool isInt = (flag == 0);

  int p = blockIdx.x*blockDim.x + threadIdx.x;
  if (p >= NP) return;
  int b = p >> 8, ts = p & (NTS-1);
  int t0 = b*NT + ts*NSTRIDE;
  bool allm;
  if (isInt) {
    const int* m32 = (const int*)m8;
    allm = m32[t0] && m32[t0+1] && m32[t0+2] && m32[t0+3];
  } else {
    allm = m8[t0] && m8[t0+1] && m8[t0+2] && m8[t0+3];
  }
  int ls = (lens[b] - NSTACK)/NSTRIDE + 1;
  if (ls < 0) ls = 0;
  if (allm && ts < ls) {
    unsigned idx = atomicAdd(&ws->nA, 1u);
    ws->activeList[idx] = p;
  }
}

// ---- fused: latents (stack+LN+proj) AND fragment-order enc bf16 split ----
__global__ __launch_bounds__(256) void k_latprep(
    const float* __restrict__ feats, const float* __restrict__ mean,
    const float* __restrict__ istd, const float* __restrict__ projw,
    const float* __restrict__ enc, Ws* ws) {
  int nA = (int)ws->nA;
  int ai = blockIdx.x;
  int limit = ((nA + (MT*16 - 1)) / (MT*16)) * (MT*16);
  int tid = threadIdx.x;

  if (ai >= nA) {
    if (ai < limit && tid < 64) {     // zero-pad fragment rows
      short8 z;
      #pragma unroll
      for (int j = 0; j < 8; ++j) z[j] = 0;
      *reinterpret_cast<short8*>(ws->aHiT + ((size_t)tid*ROWS_MAX + ai)*8) = z;
      *reinterpret_cast<short8*>(ws->aLoT + ((size_t)tid*ROWS_MAX + ai)*8) = z;
    }
    return;
  }

  int p = ws->activeList[ai];
  // ---- enc row -> bf16 hi/lo in fragment order (threads 0..63) ----
  if (tid < 64) {
    const float* src = enc + (size_t)p*ND + tid*8;
    float4 x0 = *reinterpret_cast<const float4*>(src);
    float4 x1 = *reinterpret_cast<const float4*>(src + 4);
    float xv[8] = {x0.x, x0.y, x0.z, x0.w, x1.x, x1.y, x1.z, x1.w};
    short8 h, l;
    #pragma unroll
    for (int j = 0; j < 8; ++j) {
      unsigned short hi = bf16_rne(xv[j]);
      float rem = xv[j] - __uint_as_float((unsigned)hi << 16);
      h[j] = (short)hi;
      l[j] = (short)bf16_rne(rem);
    }
    *reinterpret_cast<short8*>(ws->aHiT + ((size_t)tid*ROWS_MAX + ai)*8) = h;
    *reinterpret_cast<short8*>(ws->aLoT + ((size_t)tid*ROWS_MAX + ai)*8) = l;
  }

  // ---- latent ----
  int b = p >> 8, ts = p & (NTS-1);
  __shared__ float sN[SFD];
  __shared__ float sPart[4*64];
  __shared__ float rS[4], rQ[4];

  for (int j = tid; j < SFD; j += 256) {
    int k = j / NF, f = j - k*NF;
    sN[j] = (feats[((size_t)b*NT + ts*NSTRIDE + k)*NF + f] - mean[f]) * istd[f];
  }
  __syncthreads();
  float s = 0.f, q = 0.f;
  for (int j = tid; j < SFD; j += 256) { float x = sN[j]; s += x; q += x*x; }
  for (int o = 32; o; o >>= 1) { s += __shfl_down(s, o); q += __shfl_down(q, o); }
  if ((tid & 63) == 0) { rS[tid>>6] = s; rQ[tid>>6] = q; }
  __syncthreads();
  float mu  = (rS[0]+rS[1]+rS[2]+rS[3]) * (1.f/SFD);
  float var = (rQ[0]+rQ[1]+rQ[2]+rQ[3]) * (1.f/SFD) - mu*mu;
  float inv = rsqrtf(var + LNEPS);
  for (int j = tid; j < SFD; j += 256) sN[j] = (sN[j]-mu)*inv;
  __syncthreads();
  {
    int j = tid & 63, part = tid >> 6;
    float a = 0.f;
    int i0 = part*80;
    for (int i = i0; i < i0+80; ++i) a = fmaf(sN[i], projw[i*64 + j], a);
    sPart[part*64 + j] = a;
  }
  __syncthreads();
  if (tid < 64)
    ws->lat[ai][tid] = sPart[tid] + sPart[64+tid] + sPart[128+tid] + sPart[192+tid];
}

// ---- codebook argmin, c-parallel; spread atomicMin (8 slots) ----
__global__ __launch_bounds__(256) void k_qdist(const float* __restrict__ emb, Ws* ws) {
  int nA = (int)ws->nA;
  if (nA == 0) return;
  int tid = threadIdx.x;
  int g = tid >> 6, lane = tid & 63;
  int c = blockIdx.x * 64 + lane;
  int per = (nA + 1) >> 1;
  int a0 = blockIdx.y * per;
  int a1 = min(nA, a0 + per);
  int slot = blockIdx.x & (QS-1);

  const float4* e4 = reinterpret_cast<const float4*>(emb + ((size_t)c*NG + g)*NE);
  float4 b0 = e4[0], b1 = e4[1], b2 = e4[2], b3 = e4[3];
  float n2 = b0.x*b0.x + b0.y*b0.y + b0.z*b0.z + b0.w*b0.w
           + b1.x*b1.x + b1.y*b1.y + b1.z*b1.z + b1.w*b1.w
           + b2.x*b2.x + b2.y*b2.y + b2.z*b2.z + b2.w*b2.w
           + b3.x*b3.x + b3.y*b3.y + b3.z*b3.z + b3.w*b3.w;

  __shared__ float sL[QCH][64];
  for (int base = a0; base < a1; base += QCH) {
    int cnt = min(QCH, a1 - base);
    __syncthreads();
    for (int i = tid; i < cnt*64; i += 256)
      (&sL[0][0])[i] = (&ws->lat[0][0])[(size_t)(base + (i >> 6))*64 + (i & 63)];
    __syncthreads();
    for (int i = 0; i < cnt; ++i) {
      const float* lp = &sL[i][g*NE];
      float dot = lp[0]*b0.x + lp[1]*b0.y + lp[2]*b0.z + lp[3]*b0.w
                + lp[4]*b1.x + lp[5]*b1.y + lp[6]*b1.z + lp[7]*b1.w
                + lp[8]*b2.x + lp[9]*b2.y + lp[10]*b2.z + lp[11]*b2.w
                + lp[12]*b3.x + lp[13]*b3.y + lp[14]*b3.z + lp[15]*b3.w;
      float d = n2 - 2.f*dot;
      float mv = d; int mc = c;
      #pragma unroll
      for (int off = 32; off; off >>= 1) {
        float ov = __shfl_xor(mv, off);
        int   oc = __shfl_xor(mc, off);
        if (ov < mv || (ov == mv && oc < mc)) { mv = ov; mc = oc; }
      }
      if (lane == 0) {
        unsigned long long key =
            ((unsigned long long)fkey_asc(mv) << 32) | (unsigned)mc;
        atomicMin(&ws->aminS[(size_t)((base + i)*NG + g)*QS + slot], key);
      }
    }
  }
}

// ---- extract targets + uniq bitmap from spread slots ----
__global__ void k_tgt(Ws* ws) {
  int i = blockIdx.x*256 + threadIdx.x;
  int nA = (int)ws->nA;
  if (i < nA*NG) {
    unsigned long long m = ws->aminS[(size_t)i*QS];
    #pragma unroll
    for (int s = 1; s < QS; ++s) {
      unsigned long long v = ws->aminS[(size_t)i*QS + s];
      if (v < m) m = v;
    }
    int c = (int)(unsigned)(m & 0xFFFFFFFFull);
    ws->targets[i] = c;
    atomicOr(&ws->bitmap[c >> 5], 1u << (c & 31));
  }
}

// ---- logits GEMM: W as A-operand (direct coalesced loads), enc as B-operand
// (fragment-order layout), no LDS/barriers in k-loop, atomic-free epilogue ----
__global__ __launch_bounds__(256) void k_logits_mfma(
    const float* __restrict__ W, const float* __restrict__ bias, Ws* ws) {
  const int nA = (int)ws->nA;
  if (nA == 0) return;
  const int nSup = (nA + (MT*16 - 1)) / (MT*16);
  const int tid = threadIdx.x;
  const int wave = tid >> 6, lane = tid & 63;
  const int g = blockIdx.y;
  const int c0w = blockIdx.x * 64 + wave * 16;
  const int lo16 = lane & 15, hi4 = lane >> 4;
  const int cA = c0w + lo16;           // A-fragment column
  const int cOut0 = c0w + hi4*4;       // this lane's 4 output c's
  float bv[4];
  #pragma unroll
  for (int v = 0; v < 4; ++v) bv[v] = bias[g*NC + cOut0 + v];

  __shared__ float sEs[4][MT*16];
  __shared__ unsigned long long sMx[4][MT*16];

  for (int sup = 0; sup < nSup; ++sup) {
    const int base_m = sup * (MT*16);
    f32x4 acc[MT];
    #pragma unroll
    for (int mt = 0; mt < MT; ++mt) acc[mt] = (f32x4){0.f, 0.f, 0.f, 0.f};

    for (int ks = 0; ks < ND/32; ++ks) {
      // B fragments: contiguous 256B per 16-lane group, L2-resident
      short8 bh[MT], bl[MT];
      const size_t boff = ((size_t)(ks*4 + hi4)*ROWS_MAX + base_m + lo16)*8;
      #pragma unroll
      for (int mt = 0; mt < MT; ++mt) {
        bh[mt] = *reinterpret_cast<const short8*>(ws->aHiT + boff + (size_t)mt*128);
        bl[mt] = *reinterpret_cast<const short8*>(ws->aLoT + boff + (size_t)mt*128);
      }
      // A fragment: W[k][c], 4x64B contiguous segments per load
      const float* wp = W + ((size_t)g*ND + ks*32 + hi4*8)*NC + cA;
      float wv[8];
      #pragma unroll
      for (int j = 0; j < 8; ++j) wv[j] = wp[(size_t)j*NC];
      short8 whi, wlo;
      #pragma unroll
      for (int j = 0; j < 8; ++j) {
        unsigned short h = bf16_rne(wv[j]);
        float rem = wv[j] - __uint_as_float((unsigned)h << 16);
        whi[j] = (short)h;
        wlo[j] = (short)bf16_rne(rem);
      }
      #pragma unroll
      for (int mt = 0; mt < MT; ++mt) {
        acc[mt] = __builtin_amdgcn_mfma_f32_16x16x32_bf16(whi, bh[mt], acc[mt], 0, 0, 0);
        acc[mt] = __builtin_amdgcn_mfma_f32_16x16x32_bf16(wlo, bh[mt], acc[mt], 0, 0, 0);
        acc[mt] = __builtin_amdgcn_mfma_f32_16x16x32_bf16(whi, bl[mt], acc[mt], 0, 0, 0);
      }
    }

    // epilogue: D[m=c-local=(hi4*4+v)][n=row=lo16]
    #pragma unroll
    for (int mt = 0; mt < MT; ++mt) {
      const int row = base_m + mt*16 + lo16;
      const int tgt = (row < nA) ? ws->targets[row*NG + g] : -1;
      float lv[4];
      #pragma unroll
      for (int v = 0; v < 4; ++v) lv[v] = acc[mt][v] + bv[v];
      #pragma unroll
      for (int v = 0; v < 4; ++v)
        if (tgt == cOut0 + v) ws->tLogit[row*NG + g] = lv[v];
      float es = expf(lv[0]) + expf(lv[1]) + expf(lv[2]) + expf(lv[3]);
      float mv = lv[0]; int mi = cOut0;
      if (lv[1] > mv) { mv = lv[1]; mi = cOut0+1; }
      if (lv[2] > mv) { mv = lv[2]; mi = cOut0+2; }
      if (lv[3] > mv) { mv = lv[3]; mi = cOut0+3; }
      #pragma unroll
      for (int off = 16; off <= 32; off <<= 1) {
        es += __shfl_xor(es, off);
        float ov = __shfl_xor(mv, off);
        int   oi = __shfl_xor(mi, off);
        if (ov > mv || (ov == mv && oi < mi)) { mv = ov; mi = oi; }
      }
      if (hi4 == 0) {
        sEs[wave][mt*16 + lo16] = es;
        unsigned key = __float_as_uint(mv);
        key = (key & 0x80000000u) ? ~key : (key | 0x80000000u);
        sMx[wave][mt*16 + lo16] = ((unsigned long long)key << 32)
                                | (unsigned long long)(0xFFFFFFFFu - (unsigned)mi);
      }
    }
    __syncthreads();
    if (tid < MT*16) {
      float e = sEs[0][tid] + sEs[1][tid] + sEs[2][tid] + sEs[3][tid];
      unsigned long long m0 = sMx[0][tid], m1 = sMx[1][tid];
      unsigned long long m2 = sMx[2][tid], m3 = sMx[3][tid];
      unsigned long long ma = m0 > m1 ? m0 : m1;
      unsigned long long mb = m2 > m3 ? m2 : m3;
      unsigned long long mx = ma > mb ? ma : mb;
      int grow = base_m + tid;
      ws->part_se[g][grow][blockIdx.x] = e;
      ws->part_mx[g][grow][blockIdx.x] = mx;
    }
    __syncthreads();
  }
}

// ---- reduce 128 c-tile partials per (row,g): plain stores, no atomics ----
__global__ __launch_bounds__(256) void k_red_l(Ws* ws) {
  int nA = (int)ws->nA;
  int pair = blockIdx.x*4 + (threadIdx.x >> 6);
  int lane = threadIdx.x & 63;
  int row = pair >> 2, g = pair & 3;
  if (row >= nA) return;
  float e = ws->part_se[g][row][lane] + ws->part_se[g][row][lane + 64];
  unsigned long long a = ws->part_mx[g][row][lane];
  unsigned long long b = ws->part_mx[g][row][lane + 64];
  unsigned long long mx = a > b ? a : b;
  #pragma unroll
  for (int off = 32; off; off >>= 1) {
    e += __shfl_xor(e, off);
    unsigned long long o = __shfl_xor(mx, off);
    if (o > mx) mx = o;
  }
  if (lane == 0) {
    ws->sumExp[row*NG + g] = e;
    ws->amax[row*NG + g] = mx;
  }
}

// ======================= fallback fp32 path (round-1, proven) ==============
__global__ __launch_bounds__(256) void k_quant(
    const float* __restrict__ feats, const float* __restrict__ mean,
    const float* __restrict__ istd, const float* __restrict__ projw,
    const float* __restrict__ emb, Ws* ws) {
  if (blockIdx.x >= ws->nA) return;
  int ai = blockIdx.x;
  int p = ws->activeList[ai];
  int b = p >> 8, ts = p & (NTS-1);
  int tid = threadIdx.x;
  __shared__ float sN[SFD];
  __shared__ float sPart[4*64];
  __shared__ float sLat[NG*NE];
  __shared__ float sRedS[256];
  __shared__ int   sRedC[256];
  __shared__ float rS[4], rQ[4];
  __shared__ int   sTgt[NG];

  for (int j = tid; j < SFD; j += 256) {
    int k = j / NF, f = j - k*NF;
    sN[j] = (feats[((size_t)b*NT + ts*NSTRIDE + k)*NF + f] - mean[f]) * istd[f];
  }
  __syncthreads();
  float s = 0.f, q = 0.f;
  for (int j = tid; j < SFD; j += 256) { float x = sN[j]; s += x; q += x*x; }
  for (int o = 32; o; o >>= 1) { s += __shfl_down(s, o); q += __shfl_down(q, o); }
  if ((tid & 63) == 0) { rS[tid>>6] = s; rQ[tid>>6] = q; }
  __syncthreads();
  float mu  = (rS[0]+rS[1]+rS[2]+rS[3]) * (1.f/SFD);
  float var = (rQ[0]+rQ[1]+rQ[2]+rQ[3]) * (1.f/SFD) - mu*mu;
  float inv = rsqrtf(var + LNEPS);
  for (int j = tid; j < SFD; j += 256) sN[j] = (sN[j]-mu)*inv;
  __syncthreads();
  {
    int j = tid & 63, part = tid >> 6;
    float a = 0.f;
    int i0 = part*80;
    for (int i = i0; i < i0+80; ++i) a = fmaf(sN[i], projw[i*64 + j], a);
    sPart[part*64 + j] = a;
  }
  __syncthreads();
  if (tid < 64) sLat[tid] = sPart[tid] + sPart[64+tid] + sPart[128+tid] + sPart[192+tid];
  __syncthreads();

  for (int gg = 0; gg < NG; ++gg) {
    float lg[NE];
    #pragma unroll
    for (int e = 0; e < NE; ++e) lg[e] = sLat[gg*NE + e];
    float best = 3.4e38f; int bc = NC;
    for (int c = tid; c < NC; c += 256) {
      const float4* cb4 = reinterpret_cast<const float4*>(emb + ((size_t)c*NG + gg)*NE);
      float4 a0 = cb4[0], a1 = cb4[1], a2 = cb4[2], a3 = cb4[3];
      float dot = 0.f, n2 = 0.f;
      dot = fmaf(lg[0],  a0.x, dot); n2 = fmaf(a0.x, a0.x, n2);
      dot = fmaf(lg[1],  a0.y, dot); n2 = fmaf(a0.y, a0.y, n2);
      dot = fmaf(lg[2],  a0.z, dot); n2 = fmaf(a0.z, a0.z, n2);
      dot = fmaf(lg[3],  a0.w, dot); n2 = fmaf(a0.w, a0.w, n2);
      dot = fmaf(lg[4],  a1.x, dot); n2 = fmaf(a1.x, a1.x, n2);
      dot = fmaf(lg[5],  a1.y, dot); n2 = fmaf(a1.y, a1.y, n2);
      dot = fmaf(lg[6],  a1.z, dot); n2 = fmaf(a1.z, a1.z, n2);
      dot = fmaf(lg[7],  a1.w, dot); n2 = fmaf(a1.w, a1.w, n2);
      dot = fmaf(lg[8],  a2.x, dot); n2 = fmaf(a2.x, a2.x, n2);
      dot = fmaf(lg[9],  a2.y, dot); n2 = fmaf(a2.y, a2.y, n2);
      dot = fmaf(lg[10], a2.z, dot); n2 = fmaf(a2.z, a2.z, n2);
      dot = fmaf(lg[11], a2.w, dot); n2 = fmaf(a2.w, a2.w, n2);
      dot = fmaf(lg[12], a3.x, dot); n2 = fmaf(a3.x, a3.x, n2);
      dot = fmaf(lg[13], a3.y, dot); n2 = fmaf(a3.y, a3.y, n2);
      dot = fmaf(lg[14], a3.z, dot); n2 = fmaf(a3.z, a3.z, n2);
      dot = fmaf(lg[15], a3.w, dot); n2 = fmaf(a3.w, a3.w, n2);
      float sc = n2 - 2.f*dot;
      if (sc < best) { best = sc; bc = c; }
    }
    sRedS[tid] = best; sRedC[tid] = bc;
    __syncthreads();
    for (int off = 128; off; off >>= 1) {
      if (tid < off) {
        float os = sRedS[tid+off]; int oc = sRedC[tid+off];
        if (os < sRedS[tid] || (os == sRedS[tid] && oc < sRedC[tid])) {
          sRedS[tid] = os; sRedC[tid] = oc;
        }
      }
      __syncthreads();
    }
    if (tid == 0) sTgt[gg] = sRedC[0];
    __syncthreads();
  }
  if (tid < NG) {
    int c = sTgt[tid];
    ws->targets[ai*NG + tid] = c;
    atomicOr(&ws->bitmap[c >> 5], 1u << (c & 31));
  }
}

__global__ __launch_bounds__(256) void k_logits(
    const float* __restrict__ W, const float* __restrict__ bias,
    const float* __restrict__ enc, Ws* ws) {
  const int nA = (int)ws->nA;
  if (nA == 0) return;
  const int nCh = (nA + PCH - 1) / PCH;
  const int g = blockIdx.y;
  const int cbase = blockIdx.x * TCC + threadIdx.x * CPT;
  const float* __restrict__ Wg = W + (size_t)g*ND*NC;
  const float b0 = bias[g*NC + cbase + 0];
  const float b1 = bias[g*NC + cbase + 1];
  const float b2 = bias[g*NC + cbase + 2];
  const float b3 = bias[g*NC + cbase + 3];
  __shared__ float4 sEnc[PCH][ND/4];
  __shared__ int sP[PCH];

  for (int ch = blockIdx.z; ch < nCh; ch += PB) {
    if (threadIdx.x < PCH) {
      int ai = ch*PCH + threadIdx.x;
      sP[threadIdx.x] = (ai < nA) ? ws->activeList[ai] : -1;
    }
    __syncthreads();
    for (int i = threadIdx.x; i < PCH*(ND/4); i += 256) {
      int qq = i >> 7, r = i & 127;
      int p = sP[qq];
      sEnc[qq][r] = (p >= 0) ? reinterpret_cast<const float4*>(enc)[p*(ND/4) + r]
                             : make_float4(0.f, 0.f, 0.f, 0.f);
    }
    __syncthreads();

    float acc[PCH][CPT];
    #pragma unroll
    for (int qq = 0; qq < PCH; ++qq)
      #pragma unroll
      for (int j = 0; j < CPT; ++j) acc[qq][j] = 0.f;
    for (int d = 0; d < ND; d += 4) {
      const float* wp = Wg + (size_t)d*NC + cbase;
      float4 w0 = *reinterpret_cast<const float4*>(wp);
      float4 w1 = *reinterpret_cast<const float4*>(wp + NC);
      float4 w2 = *reinterpret_cast<const float4*>(wp + 2*NC);
      float4 w3 = *reinterpret_cast<const float4*>(wp + 3*NC);
      int dq = d >> 2;
      #pragma unroll
      for (int qq = 0; qq < PCH; ++qq) {
        float4 e = sEnc[qq][dq];
        acc[qq][0] = fmaf(e.x, w0.x, acc[qq][0]);
        acc[qq][1] = fmaf(e.x, w0.y, acc[qq][1]);
        acc[qq][2] = fmaf(e.x, w0.z, acc[qq][2]);
        acc[qq][3] = fmaf(e.x, w0.w, acc[qq][3]);
        acc[qq][0] = fmaf(e.y, w1.x, acc[qq][0]);
        acc[qq][1] = fmaf(e.y, w1.y, acc[qq][1]);
        acc[qq][2] = fmaf(e.y, w1.z, acc[qq][2]);
        acc[qq][3] = fmaf(e.y, w1.w, acc[qq][3]);
        acc[qq][0] = fmaf(e.z, w2.x, acc[qq][0]);
        acc[qq][1] = fmaf(e.z, w2.y, acc[qq][1]);
        acc[qq][2] = fmaf(e.z, w2.z, acc[qq][2]);
        acc[qq][3] = fmaf(e.z, w2.w, acc[qq][3]);
        acc[qq][0] = fmaf(e.w, w3.x, acc[qq][0]);
        acc[qq][1] = fmaf(e.w, w3.y, acc[qq][1]);
        acc[qq][2] = fmaf(e.w, w3.z, acc[qq][2]);
        acc[qq][3] = fmaf(e.w, w3.w, acc[qq][3]);
      }
    }

    #pragma unroll
    for (int qq = 0; qq < PCH; ++qq) {
      int ai = ch*PCH + qq;
      if (ai < nA) {
        float l0 = acc[qq][0] + b0;
        float l1 = acc[qq][1] + b1;
        float l2 = acc[qq][2] + b2;
        float l3 = acc[qq][3] + b3;
        int tgt = ws->targets[ai*NG + g];
        if ((unsigned)(tgt - cbase) < (unsigned)CPT) {
          float tv = (tgt == cbase) ? l0 : (tgt == cbase+1) ? l1
                   : (tgt == cbase+2) ? l2 : l3;
          ws->tLogit[ai*NG + g] = tv;
        }
        float es = expf(l0) + expf(l1) + expf(l2) + expf(l3);
        float mv = l0; int mi = cbase;
        if (l1 > mv) { mv = l1; mi = cbase+1; }
        if (l2 > mv) { mv = l2; mi = cbase+2; }
        if (l3 > mv) { mv = l3; mi = cbase+3; }
        for (int o = 32; o; o >>= 1) {
          es += __shfl_down(es, o);
          float ov = __shfl_down(mv, o);
          int   oi = __shfl_down(mi, o);
          if (ov > mv || (ov == mv && oi < mi)) { mv = ov; mi = oi; }
        }
        if ((threadIdx.x & 63) == 0) {
          atomicAdd(&ws->sumExp[ai*NG + g], es);
          unsigned key = __float_as_uint(mv);
          key = (key & 0x80000000u) ? ~key : (key | 0x80000000u);
          unsigned long long pk =
              ((unsigned long long)key << 32) |
              (unsigned long long)(0xFFFFFFFFu - (unsigned)mi);
          atomicMax(&ws->amax[ai*NG + g], pk);
        }
      }
    }
    __syncthreads();
  }
}
// ======================= end fallback =======================================

// ---- final scalar assembly ----
__global__ __launch_bounds__(256) void k_final(Ws* ws, float* __restrict__ out) {
  int tid = threadIdx.x;
  int nA = (int)ws->nA;
  float sumPer = 0.f, sumCorr = 0.f;
  for (int i = tid; i < nA*NG; i += 256) {
    sumPer += logf(ws->sumExp[i]) - ws->tLogit[i];
    unsigned long long pk = ws->amax[i];
    int mi = (int)(0xFFFFFFFFu - (unsigned)(pk & 0xFFFFFFFFull));
    if (mi == ws->targets[i]) sumCorr += 1.f;
  }
  unsigned w = ws->bitmap[tid];
  if (tid == 0 && nA < NP) w |= 1u;
  int uniq = __popc(w);

  __shared__ float rs[4], rc[4]; __shared__ int ru[4];
  float s1 = sumPer, s2 = sumCorr; int s3 = uniq;
  for (int o = 32; o; o >>= 1) {
    s1 += __shfl_down(s1, o);
    s2 += __shfl_down(s2, o);
    s3 += __shfl_down(s3, o);
  }
  if ((tid & 63) == 0) { rs[tid>>6] = s1; rc[tid>>6] = s2; ru[tid>>6] = s3; }
  __syncthreads();
  if (tid == 0) {
    float sp = rs[0]+rs[1]+rs[2]+rs[3];
    float sc = rc[0]+rc[1]+rc[2]+rc[3];
    int   un = ru[0]+ru[1]+ru[2]+ru[3];
    float pen   = ws->penSum / (float)(NB*NT*NF);
    float denom = (float)nA + 1e-5f;
    float nc    = (float)(nA * NG);
    out[0] = sp / (denom * (float)NG) + FREG * pen;
    out[1] = sc / nc;
    out[2] = pen;
    out[3] = nc;
    out[4] = (float)un;
  }
}

extern "C" void kernel_launch(void* const* d_in, const int* in_sizes, int n_in,
                              void* d_out, int out_size, void* d_ws, size_t ws_size,
                              hipStream_t stream) {
  const float* feats = (const float*)d_in[0];
  const int*   lens  = (const int*)d_in[1];
  const unsigned char* masks = (const unsigned char*)d_in[2];
  const float* mean  = (const float*)d_in[4];
  const float* istd  = (const float*)d_in[5];
  const float* projw = (const float*)d_in[6];
  const float* emb   = (const float*)d_in[7];
  const float* W     = (const float*)d_in[8];
  const float* bias  = (const float*)d_in[9];
  const float* enc   = (const float*)d_in[10];
  Ws* ws = (Ws*)d_ws;
  float* out = (float*)d_out;

  bool big = ws_size >= sizeof(Ws);
  size_t zr = offsetof(Ws, aminS);
  hipMemsetAsync(d_ws, 0, (big || ws_size >= zr) ? zr : ws_size, stream);

  k_pen<<<256, 256, 0, stream>>>(feats, mean, istd, ws);
  k_mask<<<NP/256, 256, 0, stream>>>(masks, lens, ws);

  if (big) {
    hipMemsetAsync(&ws->aminS[0], 0xFF, sizeof(ws->aminS), stream);
    k_latprep<<<ROWS_MAX, 256, 0, stream>>>(feats, mean, istd, projw, enc, ws);
    k_qdist<<<dim3(NC/64, 2), 256, 0, stream>>>(emb, ws);
    k_tgt<<<NP*NG/256, 256, 0, stream>>>(ws);
    k_logits_mfma<<<dim3(CT, NG), 256, 0, stream>>>(W, bias, ws);
    k_red_l<<<NP, 256, 0, stream>>>(ws);
  } else {
    k_quant<<<NP, 256, 0, stream>>>(feats, mean, istd, projw, emb, ws);
    k_logits<<<dim3(NC/TCC, NG, PB), 256, 0, stream>>>(W, bias, enc, ws);
  }
  k_final<<<1, 256, 0, stream>>>(ws, out);
}

// Round 5
// 114.896 us; speedup vs baseline: 5.6960x; 1.0927x over previous
//
#include <hip/hip_runtime.h>
#include <hip/hip_bf16.h>
#include <math.h>
#include <stddef.h>

// Problem constants (from reference)
#define NB 8
#define NT 1024
#define NF 80
#define NSTACK 4
#define NSTRIDE 4
#define NG 4
#define NE 16
#define NC 8192
#define ND 512
#define NTS 256          // (NT-NSTACK)/NSTRIDE + 1
#define NP (NB*NTS)      // 2048 subsampled positions
#define SFD (NSTACK*NF)  // 320
#define FREG 0.01f
#define LNEPS 1e-5f

// fp32-fallback k_logits tiling
#define TCC 1024
#define CPT 4
#define PCH 16
#define PB 16

// MFMA path
#define ROWS_MAX 2176     // >= ceil(2048/48)*48 = 2064
#define ROWCH 48          // rows per block chunk
#define MT 3              // 16-row m-tiles per chunk
#define ZB 8              // grid.z (chunk-index stride)
#define QCH 128           // lat rows staged per k_qdist pass
#define CT 128            // c-tiles of 64 for the logits GEMM partials
#define QS 8              // qdist atomic spread slots

typedef __attribute__((ext_vector_type(8))) short short8;
typedef __attribute__((ext_vector_type(4))) float f32x4;

struct Ws {
  // ---------- zero-initialized region (memset) ----------
  float penSum;
  unsigned int nA;
  unsigned int maskIsInt;
  unsigned int pad1;
  unsigned long long amax[NP*NG];   // final packed (key<<32 | ~idx) argmax
  float sumExp[NP*NG];
  float tLogit[NP*NG];
  int   targets[NP*NG];
  int   activeList[NP];
  unsigned int bitmap[NC/32];
  // ---------- initialized by k_prologue ----------
  unsigned long long aminS[NP*NG*QS]; // qdist spread argmin slots (0xFF)
  // ---------- no init needed ----------
  float lat[NP][64];
  // fragment-order bf16 splits of active encoder rows:
  // aHiT[((k/8)*ROWS_MAX + row)*8 + (k%8)]
  unsigned short aHiT[(size_t)(ND/8)*ROWS_MAX*8];
  unsigned short aLoT[(size_t)(ND/8)*ROWS_MAX*8];
  float part_se[NG][ROWS_MAX][CT];
  unsigned long long part_mx[NG][ROWS_MAX][CT];
};

__device__ inline unsigned short bf16_rne(float x) {
  unsigned u = __float_as_uint(x);
  unsigned r = u + 0x7FFFu + ((u >> 16) & 1u);
  return (unsigned short)(r >> 16);
}
__device__ inline unsigned fkey_asc(float d) {  // ascending float -> ascending uint
  unsigned u = __float_as_uint(d);
  return (u & 0x80000000u) ? ~u : (u | 0x80000000u);
}

// ---- fused prologue: features_pen + mask/compact + aminS init ----
// grid 256 x 256. All blocks: pen grid-stride + clear 1 aminS entry/thread.
// Blocks 0..7: mask+compact for 256 positions each (self-detect mask layout).
__global__ __launch_bounds__(256) void k_prologue(
    const float* __restrict__ feats, const float* __restrict__ mean,
    const float* __restrict__ istd, const unsigned char* __restrict__ m8,
    const int* __restrict__ lens, int doClear, Ws* ws) {
  const int tid = threadIdx.x;
  // aminS clear: 256*256 threads == NP*NG*QS entries
  if (doClear) ws->aminS[(size_t)blockIdx.x*256 + tid] = ~0ull;

  // features_pen
  const int N4 = NB*NT*NF/4;
  float s = 0.f;
  for (int i = blockIdx.x*256 + tid; i < N4; i += gridDim.x*256) {
    float4 v = reinterpret_cast<const float4*>(feats)[i];
    int f0 = (i*4) % NF;
    float x0 = (v.x - mean[f0+0]) * istd[f0+0];
    float x1 = (v.y - mean[f0+1]) * istd[f0+1];
    float x2 = (v.z - mean[f0+2]) * istd[f0+2];
    float x3 = (v.w - mean[f0+3]) * istd[f0+3];
    s += x0*x0 + x1*x1 + x2*x2 + x3*x3;
  }
  for (int o = 32; o; o >>= 1) s += __shfl_down(s, o);
  __shared__ float pr[4];
  if ((tid & 63) == 0) pr[tid >> 6] = s;
  __syncthreads();
  if (tid == 0) atomicAdd(&ws->penSum, pr[0]+pr[1]+pr[2]+pr[3]);

  // mask + compact (blocks 0..7)
  if (blockIdx.x < NP/256) {
    __shared__ unsigned flag;
    if (tid == 0) flag = 0;
    __syncthreads();
    unsigned nz = 0;
    int base = tid * 32;
    for (int i = base; i < base + 32; ++i)
      if ((i & 3) && m8[i]) nz = 1;
    if (nz) atomicOr(&flag, 1u);
    __syncthreads();
    bool isInt = (flag == 0);

    int p = blockIdx.x*256 + tid;
    int b = p >> 8, ts = p & (NTS-1);
    int t0 = b*NT + ts*NSTRIDE;
    bool allm;
    if (isInt) {
      const int* m32 = (const int*)m8;
      allm = m32[t0] && m32[t0+1] && m32[t0+2] && m32[t0+3];
    } else {
      allm = m8[t0] && m8[t0+1] && m8[t0+2] && m8[t0+3];
    }
    int ls = (lens[b] - NSTACK)/NSTRIDE + 1;
    if (ls < 0) ls = 0;
    if (allm && ts < ls) {
      unsigned idx = atomicAdd(&ws->nA, 1u);
      ws->activeList[idx] = p;
    }
  }
}

// ---- fused: latents (stack+LN+proj) AND fragment-order enc bf16 split ----
__global__ __launch_bounds__(256) void k_latprep(
    const float* __restrict__ feats, const float* __restrict__ mean,
    const float* __restrict__ istd, const float* __restrict__ projw,
    const float* __restrict__ enc, Ws* ws) {
  int nA = (int)ws->nA;
  int ai = blockIdx.x;
  int limit = ((nA + ROWCH - 1) / ROWCH) * ROWCH;
  int tid = threadIdx.x;

  if (ai >= nA) {
    if (ai < limit && tid < 64) {     // zero-pad fragment rows
      short8 z;
      #pragma unroll
      for (int j = 0; j < 8; ++j) z[j] = 0;
      *reinterpret_cast<short8*>(ws->aHiT + ((size_t)tid*ROWS_MAX + ai)*8) = z;
      *reinterpret_cast<short8*>(ws->aLoT + ((size_t)tid*ROWS_MAX + ai)*8) = z;
    }
    return;
  }

  int p = ws->activeList[ai];
  // ---- enc row -> bf16 hi/lo in fragment order (threads 0..63) ----
  if (tid < 64) {
    const float* src = enc + (size_t)p*ND + tid*8;
    float4 x0 = *reinterpret_cast<const float4*>(src);
    float4 x1 = *reinterpret_cast<const float4*>(src + 4);
    float xv[8] = {x0.x, x0.y, x0.z, x0.w, x1.x, x1.y, x1.z, x1.w};
    short8 h, l;
    #pragma unroll
    for (int j = 0; j < 8; ++j) {
      unsigned short hi = bf16_rne(xv[j]);
      float rem = xv[j] - __uint_as_float((unsigned)hi << 16);
      h[j] = (short)hi;
      l[j] = (short)bf16_rne(rem);
    }
    *reinterpret_cast<short8*>(ws->aHiT + ((size_t)tid*ROWS_MAX + ai)*8) = h;
    *reinterpret_cast<short8*>(ws->aLoT + ((size_t)tid*ROWS_MAX + ai)*8) = l;
  }

  // ---- latent ----
  int b = p >> 8, ts = p & (NTS-1);
  __shared__ float sN[SFD];
  __shared__ float sPart[4*64];
  __shared__ float rS[4], rQ[4];

  for (int j = tid; j < SFD; j += 256) {
    int k = j / NF, f = j - k*NF;
    sN[j] = (feats[((size_t)b*NT + ts*NSTRIDE + k)*NF + f] - mean[f]) * istd[f];
  }
  __syncthreads();
  float s = 0.f, q = 0.f;
  for (int j = tid; j < SFD; j += 256) { float x = sN[j]; s += x; q += x*x; }
  for (int o = 32; o; o >>= 1) { s += __shfl_down(s, o); q += __shfl_down(q, o); }
  if ((tid & 63) == 0) { rS[tid>>6] = s; rQ[tid>>6] = q; }
  __syncthreads();
  float mu  = (rS[0]+rS[1]+rS[2]+rS[3]) * (1.f/SFD);
  float var = (rQ[0]+rQ[1]+rQ[2]+rQ[3]) * (1.f/SFD) - mu*mu;
  float inv = rsqrtf(var + LNEPS);
  for (int j = tid; j < SFD; j += 256) sN[j] = (sN[j]-mu)*inv;
  __syncthreads();
  {
    int j = tid & 63, part = tid >> 6;
    float a = 0.f;
    int i0 = part*80;
    for (int i = i0; i < i0+80; ++i) a = fmaf(sN[i], projw[i*64 + j], a);
    sPart[part*64 + j] = a;
  }
  __syncthreads();
  if (tid < 64)
    ws->lat[ai][tid] = sPart[tid] + sPart[64+tid] + sPart[128+tid] + sPart[192+tid];
}

// ---- codebook argmin, c-parallel; spread atomicMin (8 slots) ----
__global__ __launch_bounds__(256) void k_qdist(const float* __restrict__ emb, Ws* ws) {
  int nA = (int)ws->nA;
  if (nA == 0) return;
  int tid = threadIdx.x;
  int g = tid >> 6, lane = tid & 63;
  int c = blockIdx.x * 64 + lane;
  int per = (nA + 1) >> 1;
  int a0 = blockIdx.y * per;
  int a1 = min(nA, a0 + per);
  int slot = blockIdx.x & (QS-1);

  const float4* e4 = reinterpret_cast<const float4*>(emb + ((size_t)c*NG + g)*NE);
  float4 b0 = e4[0], b1 = e4[1], b2 = e4[2], b3 = e4[3];
  float n2 = b0.x*b0.x + b0.y*b0.y + b0.z*b0.z + b0.w*b0.w
           + b1.x*b1.x + b1.y*b1.y + b1.z*b1.z + b1.w*b1.w
           + b2.x*b2.x + b2.y*b2.y + b2.z*b2.z + b2.w*b2.w
           + b3.x*b3.x + b3.y*b3.y + b3.z*b3.z + b3.w*b3.w;

  __shared__ float sL[QCH][64];
  for (int base = a0; base < a1; base += QCH) {
    int cnt = min(QCH, a1 - base);
    __syncthreads();
    for (int i = tid; i < cnt*64; i += 256)
      (&sL[0][0])[i] = (&ws->lat[0][0])[(size_t)(base + (i >> 6))*64 + (i & 63)];
    __syncthreads();
    for (int i = 0; i < cnt; ++i) {
      const float* lp = &sL[i][g*NE];
      float dot = lp[0]*b0.x + lp[1]*b0.y + lp[2]*b0.z + lp[3]*b0.w
                + lp[4]*b1.x + lp[5]*b1.y + lp[6]*b1.z + lp[7]*b1.w
                + lp[8]*b2.x + lp[9]*b2.y + lp[10]*b2.z + lp[11]*b2.w
                + lp[12]*b3.x + lp[13]*b3.y + lp[14]*b3.z + lp[15]*b3.w;
      float d = n2 - 2.f*dot;
      float mv = d; int mc = c;
      #pragma unroll
      for (int off = 32; off; off >>= 1) {
        float ov = __shfl_xor(mv, off);
        int   oc = __shfl_xor(mc, off);
        if (ov < mv || (ov == mv && oc < mc)) { mv = ov; mc = oc; }
      }
      if (lane == 0) {
        unsigned long long key =
            ((unsigned long long)fkey_asc(mv) << 32) | (unsigned)mc;
        atomicMin(&ws->aminS[(size_t)((base + i)*NG + g)*QS + slot], key);
      }
    }
  }
}

// ---- extract targets + uniq bitmap from spread slots ----
__global__ void k_tgt(Ws* ws) {
  int i = blockIdx.x*256 + threadIdx.x;
  int nA = (int)ws->nA;
  if (i < nA*NG) {
    unsigned long long m = ws->aminS[(size_t)i*QS];
    #pragma unroll
    for (int s = 1; s < QS; ++s) {
      unsigned long long v = ws->aminS[(size_t)i*QS + s];
      if (v < m) m = v;
    }
    int c = (int)(unsigned)(m & 0xFFFFFFFFull);
    ws->targets[i] = c;
    atomicOr(&ws->bitmap[c >> 5], 1u << (c & 31));
  }
}

// ---- logits GEMM: W as A-operand (direct coalesced loads), enc as B-operand
// (fragment-order layout), 48-row chunks for TLP, atomic-free epilogue ----
__global__ __launch_bounds__(256) void k_logits_mfma(
    const float* __restrict__ W, const float* __restrict__ bias, Ws* ws) {
  const int nA = (int)ws->nA;
  if (nA == 0) return;
  const int nCh = (nA + ROWCH - 1) / ROWCH;
  const int tid = threadIdx.x;
  const int wave = tid >> 6, lane = tid & 63;
  const int g = blockIdx.y;
  const int c0w = blockIdx.x * 64 + wave * 16;
  const int lo16 = lane & 15, hi4 = lane >> 4;
  const int cA = c0w + lo16;           // A-fragment column
  const int cOut0 = c0w + hi4*4;       // this lane's 4 output c's
  float bv[4];
  #pragma unroll
  for (int v = 0; v < 4; ++v) bv[v] = bias[g*NC + cOut0 + v];

  __shared__ float sEs[4][ROWCH];
  __shared__ unsigned long long sMx[4][ROWCH];

  for (int ch = blockIdx.z; ch < nCh; ch += ZB) {
    const int r0 = ch * ROWCH;
    f32x4 acc[MT];
    #pragma unroll
    for (int mt = 0; mt < MT; ++mt) acc[mt] = (f32x4){0.f, 0.f, 0.f, 0.f};

    for (int ks = 0; ks < ND/32; ++ks) {
      // B fragments: contiguous 256B per 16-lane group, L1/L2-resident
      short8 bh[MT], bl[MT];
      const size_t boff = ((size_t)(ks*4 + hi4)*ROWS_MAX + r0 + lo16)*8;
      #pragma unroll
      for (int mt = 0; mt < MT; ++mt) {
        bh[mt] = *reinterpret_cast<const short8*>(ws->aHiT + boff + (size_t)mt*128);
        bl[mt] = *reinterpret_cast<const short8*>(ws->aLoT + boff + (size_t)mt*128);
      }
      // A fragment: W[k][c], 4x64B contiguous segments per load
      const float* wp = W + ((size_t)g*ND + ks*32 + hi4*8)*NC + cA;
      float wv[8];
      #pragma unroll
      for (int j = 0; j < 8; ++j) wv[j] = wp[(size_t)j*NC];
      short8 whi, wlo;
      #pragma unroll
      for (int j = 0; j < 8; ++j) {
        unsigned short h = bf16_rne(wv[j]);
        float rem = wv[j] - __uint_as_float((unsigned)h << 16);
        whi[j] = (short)h;
        wlo[j] = (short)bf16_rne(rem);
      }
      #pragma unroll
      for (int mt = 0; mt < MT; ++mt) {
        acc[mt] = __builtin_amdgcn_mfma_f32_16x16x32_bf16(whi, bh[mt], acc[mt], 0, 0, 0);
        acc[mt] = __builtin_amdgcn_mfma_f32_16x16x32_bf16(wlo, bh[mt], acc[mt], 0, 0, 0);
        acc[mt] = __builtin_amdgcn_mfma_f32_16x16x32_bf16(whi, bl[mt], acc[mt], 0, 0, 0);
      }
    }

    // epilogue: D[m=c-local=(hi4*4+v)][n=row=lo16]
    #pragma unroll
    for (int mt = 0; mt < MT; ++mt) {
      const int row = r0 + mt*16 + lo16;
      const int tgt = (row < nA) ? ws->targets[row*NG + g] : -1;
      float lv[4];
      #pragma unroll
      for (int v = 0; v < 4; ++v) lv[v] = acc[mt][v] + bv[v];
      #pragma unroll
      for (int v = 0; v < 4; ++v)
        if (tgt == cOut0 + v) ws->tLogit[row*NG + g] = lv[v];
      float es = expf(lv[0]) + expf(lv[1]) + expf(lv[2]) + expf(lv[3]);
      float mv = lv[0]; int mi = cOut0;
      if (lv[1] > mv) { mv = lv[1]; mi = cOut0+1; }
      if (lv[2] > mv) { mv = lv[2]; mi = cOut0+2; }
      if (lv[3] > mv) { mv = lv[3]; mi = cOut0+3; }
      #pragma unroll
      for (int off = 16; off <= 32; off <<= 1) {
        es += __shfl_xor(es, off);
        float ov = __shfl_xor(mv, off);
        int   oi = __shfl_xor(mi, off);
        if (ov > mv || (ov == mv && oi < mi)) { mv = ov; mi = oi; }
      }
      if (hi4 == 0) {
        sEs[wave][mt*16 + lo16] = es;
        unsigned key = __float_as_uint(mv);
        key = (key & 0x80000000u) ? ~key : (key | 0x80000000u);
        sMx[wave][mt*16 + lo16] = ((unsigned long long)key << 32)
                                | (unsigned long long)(0xFFFFFFFFu - (unsigned)mi);
      }
    }
    __syncthreads();
    if (tid < ROWCH) {
      float e = sEs[0][tid] + sEs[1][tid] + sEs[2][tid] + sEs[3][tid];
      unsigned long long m0 = sMx[0][tid], m1 = sMx[1][tid];
      unsigned long long m2 = sMx[2][tid], m3 = sMx[3][tid];
      unsigned long long ma = m0 > m1 ? m0 : m1;
      unsigned long long mb = m2 > m3 ? m2 : m3;
      unsigned long long mx = ma > mb ? ma : mb;
      int grow = r0 + tid;
      ws->part_se[g][grow][blockIdx.x] = e;
      ws->part_mx[g][grow][blockIdx.x] = mx;
    }
    __syncthreads();
  }
}

// ---- reduce 128 c-tile partials per (row,g): plain stores, no atomics ----
__global__ __launch_bounds__(256) void k_red_l(Ws* ws) {
  int nA = (int)ws->nA;
  int pair = blockIdx.x*4 + (threadIdx.x >> 6);
  int lane = threadIdx.x & 63;
  int row = pair >> 2, g = pair & 3;
  if (row >= nA) return;
  float e = ws->part_se[g][row][lane] + ws->part_se[g][row][lane + 64];
  unsigned long long a = ws->part_mx[g][row][lane];
  unsigned long long b = ws->part_mx[g][row][lane + 64];
  unsigned long long mx = a > b ? a : b;
  #pragma unroll
  for (int off = 32; off; off >>= 1) {
    e += __shfl_xor(e, off);
    unsigned long long o = __shfl_xor(mx, off);
    if (o > mx) mx = o;
  }
  if (lane == 0) {
    ws->sumExp[row*NG + g] = e;
    ws->amax[row*NG + g] = mx;
  }
}

// ======================= fallback fp32 path (round-1, proven) ==============
__global__ __launch_bounds__(256) void k_quant(
    const float* __restrict__ feats, const float* __restrict__ mean,
    const float* __restrict__ istd, const float* __restrict__ projw,
    const float* __restrict__ emb, Ws* ws) {
  if (blockIdx.x >= ws->nA) return;
  int ai = blockIdx.x;
  int p = ws->activeList[ai];
  int b = p >> 8, ts = p & (NTS-1);
  int tid = threadIdx.x;
  __shared__ float sN[SFD];
  __shared__ float sPart[4*64];
  __shared__ float sLat[NG*NE];
  __shared__ float sRedS[256];
  __shared__ int   sRedC[256];
  __shared__ float rS[4], rQ[4];
  __shared__ int   sTgt[NG];

  for (int j = tid; j < SFD; j += 256) {
    int k = j / NF, f = j - k*NF;
    sN[j] = (feats[((size_t)b*NT + ts*NSTRIDE + k)*NF + f] - mean[f]) * istd[f];
  }
  __syncthreads();
  float s = 0.f, q = 0.f;
  for (int j = tid; j < SFD; j += 256) { float x = sN[j]; s += x; q += x*x; }
  for (int o = 32; o; o >>= 1) { s += __shfl_down(s, o); q += __shfl_down(q, o); }
  if ((tid & 63) == 0) { rS[tid>>6] = s; rQ[tid>>6] = q; }
  __syncthreads();
  float mu  = (rS[0]+rS[1]+rS[2]+rS[3]) * (1.f/SFD);
  float var = (rQ[0]+rQ[1]+rQ[2]+rQ[3]) * (1.f/SFD) - mu*mu;
  float inv = rsqrtf(var + LNEPS);
  for (int j = tid; j < SFD; j += 256) sN[j] = (sN[j]-mu)*inv;
  __syncthreads();
  {
    int j = tid & 63, part = tid >> 6;
    float a = 0.f;
    int i0 = part*80;
    for (int i = i0; i < i0+80; ++i) a = fmaf(sN[i], projw[i*64 + j], a);
    sPart[part*64 + j] = a;
  }
  __syncthreads();
  if (tid < 64) sLat[tid] = sPart[tid] + sPart[64+tid] + sPart[128+tid] + sPart[192+tid];
  __syncthreads();

  for (int gg = 0; gg < NG; ++gg) {
    float lg[NE];
    #pragma unroll
    for (int e = 0; e < NE; ++e) lg[e] = sLat[gg*NE + e];
    float best = 3.4e38f; int bc = NC;
    for (int c = tid; c < NC; c += 256) {
      const float4* cb4 = reinterpret_cast<const float4*>(emb + ((size_t)c*NG + gg)*NE);
      float4 a0 = cb4[0], a1 = cb4[1], a2 = cb4[2], a3 = cb4[3];
      float dot = 0.f, n2 = 0.f;
      dot = fmaf(lg[0],  a0.x, dot); n2 = fmaf(a0.x, a0.x, n2);
      dot = fmaf(lg[1],  a0.y, dot); n2 = fmaf(a0.y, a0.y, n2);
      dot = fmaf(lg[2],  a0.z, dot); n2 = fmaf(a0.z, a0.z, n2);
      dot = fmaf(lg[3],  a0.w, dot); n2 = fmaf(a0.w, a0.w, n2);
      dot = fmaf(lg[4],  a1.x, dot); n2 = fmaf(a1.x, a1.x, n2);
      dot = fmaf(lg[5],  a1.y, dot); n2 = fmaf(a1.y, a1.y, n2);
      dot = fmaf(lg[6],  a1.z, dot); n2 = fmaf(a1.z, a1.z, n2);
      dot = fmaf(lg[7],  a1.w, dot); n2 = fmaf(a1.w, a1.w, n2);
      dot = fmaf(lg[8],  a2.x, dot); n2 = fmaf(a2.x, a2.x, n2);
      dot = fmaf(lg[9],  a2.y, dot); n2 = fmaf(a2.y, a2.y, n2);
      dot = fmaf(lg[10], a2.z, dot); n2 = fmaf(a2.z, a2.z, n2);
      dot = fmaf(lg[11], a2.w, dot); n2 = fmaf(a2.w, a2.w, n2);
      dot = fmaf(lg[12], a3.x, dot); n2 = fmaf(a3.x, a3.x, n2);
      dot = fmaf(lg[13], a3.y, dot); n2 = fmaf(a3.y, a3.y, n2);
      dot = fmaf(lg[14], a3.z, dot); n2 = fmaf(a3.z, a3.z, n2);
      dot = fmaf(lg[15], a3.w, dot); n2 = fmaf(a3.w, a3.w, n2);
      float sc = n2 - 2.f*dot;
      if (sc < best) { best = sc; bc = c; }
    }
    sRedS[tid] = best; sRedC[tid] = bc;
    __syncthreads();
    for (int off = 128; off; off >>= 1) {
      if (tid < off) {
        float os = sRedS[tid+off]; int oc = sRedC[tid+off];
        if (os < sRedS[tid] || (os == sRedS[tid] && oc < sRedC[tid])) {
          sRedS[tid] = os; sRedC[tid] = oc;
        }
      }
      __syncthreads();
    }
    if (tid == 0) sTgt[gg] = sRedC[0];
    __syncthreads();
  }
  if (tid < NG) {
    int c = sTgt[tid];
    ws->targets[ai*NG + tid] = c;
    atomicOr(&ws->bitmap[c >> 5], 1u << (c & 31));
  }
}

__global__ __launch_bounds__(256) void k_logits(
    const float* __restrict__ W, const float* __restrict__ bias,
    const float* __restrict__ enc, Ws* ws) {
  const int nA = (int)ws->nA;
  if (nA == 0) return;
  const int nCh = (nA + PCH - 1) / PCH;
  const int g = blockIdx.y;
  const int cbase = blockIdx.x * TCC + threadIdx.x * CPT;
  const float* __restrict__ Wg = W + (size_t)g*ND*NC;
  const float b0 = bias[g*NC + cbase + 0];
  const float b1 = bias[g*NC + cbase + 1];
  const float b2 = bias[g*NC + cbase + 2];
  const float b3 = bias[g*NC + cbase + 3];
  __shared__ float4 sEnc[PCH][ND/4];
  __shared__ int sP[PCH];

  for (int ch = blockIdx.z; ch < nCh; ch += PB) {
    if (threadIdx.x < PCH) {
      int ai = ch*PCH + threadIdx.x;
      sP[threadIdx.x] = (ai < nA) ? ws->activeList[ai] : -1;
    }
    __syncthreads();
    for (int i = threadIdx.x; i < PCH*(ND/4); i += 256) {
      int qq = i >> 7, r = i & 127;
      int p = sP[qq];
      sEnc[qq][r] = (p >= 0) ? reinterpret_cast<const float4*>(enc)[p*(ND/4) + r]
                             : make_float4(0.f, 0.f, 0.f, 0.f);
    }
    __syncthreads();

    float acc[PCH][CPT];
    #pragma unroll
    for (int qq = 0; qq < PCH; ++qq)
      #pragma unroll
      for (int j = 0; j < CPT; ++j) acc[qq][j] = 0.f;
    for (int d = 0; d < ND; d += 4) {
      const float* wp = Wg + (size_t)d*NC + cbase;
      float4 w0 = *reinterpret_cast<const float4*>(wp);
      float4 w1 = *reinterpret_cast<const float4*>(wp + NC);
      float4 w2 = *reinterpret_cast<const float4*>(wp + 2*NC);
      float4 w3 = *reinterpret_cast<const float4*>(wp + 3*NC);
      int dq = d >> 2;
      #pragma unroll
      for (int qq = 0; qq < PCH; ++qq) {
        float4 e = sEnc[qq][dq];
        acc[qq][0] = fmaf(e.x, w0.x, acc[qq][0]);
        acc[qq][1] = fmaf(e.x, w0.y, acc[qq][1]);
        acc[qq][2] = fmaf(e.x, w0.z, acc[qq][2]);
        acc[qq][3] = fmaf(e.x, w0.w, acc[qq][3]);
        acc[qq][0] = fmaf(e.y, w1.x, acc[qq][0]);
        acc[qq][1] = fmaf(e.y, w1.y, acc[qq][1]);
        acc[qq][2] = fmaf(e.y, w1.z, acc[qq][2]);
        acc[qq][3] = fmaf(e.y, w1.w, acc[qq][3]);
        acc[qq][0] = fmaf(e.z, w2.x, acc[qq][0]);
        acc[qq][1] = fmaf(e.z, w2.y, acc[qq][1]);
        acc[qq][2] = fmaf(e.z, w2.z, acc[qq][2]);
        acc[qq][3] = fmaf(e.z, w2.w, acc[qq][3]);
        acc[qq][0] = fmaf(e.w, w3.x, acc[qq][0]);
        acc[qq][1] = fmaf(e.w, w3.y, acc[qq][1]);
        acc[qq][2] = fmaf(e.w, w3.z, acc[qq][2]);
        acc[qq][3] = fmaf(e.w, w3.w, acc[qq][3]);
      }
    }

    #pragma unroll
    for (int qq = 0; qq < PCH; ++qq) {
      int ai = ch*PCH + qq;
      if (ai < nA) {
        float l0 = acc[qq][0] + b0;
        float l1 = acc[qq][1] + b1;
        float l2 = acc[qq][2] + b2;
        float l3 = acc[qq][3] + b3;
        int tgt = ws->targets[ai*NG + g];
        if ((unsigned)(tgt - cbase) < (unsigned)CPT) {
          float tv = (tgt == cbase) ? l0 : (tgt == cbase+1) ? l1
                   : (tgt == cbase+2) ? l2 : l3;
          ws->tLogit[ai*NG + g] = tv;
        }
        float es = expf(l0) + expf(l1) + expf(l2) + expf(l3);
        float mv = l0; int mi = cbase;
        if (l1 > mv) { mv = l1; mi = cbase+1; }
        if (l2 > mv) { mv = l2; mi = cbase+2; }
        if (l3 > mv) { mv = l3; mi = cbase+3; }
        for (int o = 32; o; o >>= 1) {
          es += __shfl_down(es, o);
          float ov = __shfl_down(mv, o);
          int   oi = __shfl_down(mi, o);
          if (ov > mv || (ov == mv && oi < mi)) { mv = ov; mi = oi; }
        }
        if ((threadIdx.x & 63) == 0) {
          atomicAdd(&ws->sumExp[ai*NG + g], es);
          unsigned key = __float_as_uint(mv);
          key = (key & 0x80000000u) ? ~key : (key | 0x80000000u);
          unsigned long long pk =
              ((unsigned long long)key << 32) |
              (unsigned long long)(0xFFFFFFFFu - (unsigned)mi);
          atomicMax(&ws->amax[ai*NG + g], pk);
        }
      }
    }
    __syncthreads();
  }
}
// ======================= end fallback =======================================

// ---- final scalar assembly ----
__global__ __launch_bounds__(256) void k_final(Ws* ws, float* __restrict__ out) {
  int tid = threadIdx.x;
  int nA = (int)ws->nA;
  float sumPer = 0.f, sumCorr = 0.f;
  for (int i = tid; i < nA*NG; i += 256) {
    sumPer += logf(ws->sumExp[i]) - ws->tLogit[i];
    unsigned long long pk = ws->amax[i];
    int mi = (int)(0xFFFFFFFFu - (unsigned)(pk & 0xFFFFFFFFull));
    if (mi == ws->targets[i]) sumCorr += 1.f;
  }
  unsigned w = ws->bitmap[tid];
  if (tid == 0 && nA < NP) w |= 1u;
  int uniq = __popc(w);

  __shared__ float rs[4], rc[4]; __shared__ int ru[4];
  float s1 = sumPer, s2 = sumCorr; int s3 = uniq;
  for (int o = 32; o; o >>= 1) {
    s1 += __shfl_down(s1, o);
    s2 += __shfl_down(s2, o);
    s3 += __shfl_down(s3, o);
  }
  if ((tid & 63) == 0) { rs[tid>>6] = s1; rc[tid>>6] = s2; ru[tid>>6] = s3; }
  __syncthreads();
  if (tid == 0) {
    float sp = rs[0]+rs[1]+rs[2]+rs[3];
    float sc = rc[0]+rc[1]+rc[2]+rc[3];
    int   un = ru[0]+ru[1]+ru[2]+ru[3];
    float pen   = ws->penSum / (float)(NB*NT*NF);
    float denom = (float)nA + 1e-5f;
    float nc    = (float)(nA * NG);
    out[0] = sp / (denom * (float)NG) + FREG * pen;
    out[1] = sc / nc;
    out[2] = pen;
    out[3] = nc;
    out[4] = (float)un;
  }
}

extern "C" void kernel_launch(void* const* d_in, const int* in_sizes, int n_in,
                              void* d_out, int out_size, void* d_ws, size_t ws_size,
                              hipStream_t stream) {
  const float* feats = (const float*)d_in[0];
  const int*   lens  = (const int*)d_in[1];
  const unsigned char* masks = (const unsigned char*)d_in[2];
  const float* mean  = (const float*)d_in[4];
  const float* istd  = (const float*)d_in[5];
  const float* projw = (const float*)d_in[6];
  const float* emb   = (const float*)d_in[7];
  const float* W     = (const float*)d_in[8];
  const float* bias  = (const float*)d_in[9];
  const float* enc   = (const float*)d_in[10];
  Ws* ws = (Ws*)d_ws;
  float* out = (float*)d_out;

  bool big = ws_size >= sizeof(Ws);
  size_t zr = offsetof(Ws, aminS);
  hipMemsetAsync(d_ws, 0, (big || ws_size >= zr) ? zr : ws_size, stream);

  k_prologue<<<256, 256, 0, stream>>>(feats, mean, istd, masks, lens,
                                      big ? 1 : 0, ws);

  if (big) {
    k_latprep<<<ROWS_MAX, 256, 0, stream>>>(feats, mean, istd, projw, enc, ws);
    k_qdist<<<dim3(NC/64, 2), 256, 0, stream>>>(emb, ws);
    k_tgt<<<NP*NG/256, 256, 0, stream>>>(ws);
    k_logits_mfma<<<dim3(CT, NG, ZB), 256, 0, stream>>>(W, bias, ws);
    k_red_l<<<NP, 256, 0, stream>>>(ws);
  } else {
    k_quant<<<NP, 256, 0, stream>>>(feats, mean, istd, projw, emb, ws);
    k_logits<<<dim3(NC/TCC, NG, PB), 256, 0, stream>>>(W, bias, enc, ws);
  }
  k_final<<<1, 256, 0, stream>>>(ws, out);
}

// Round 6
// 111.372 us; speedup vs baseline: 5.8762x; 1.0316x over previous
//
#include <hip/hip_runtime.h>
#include <hip/hip_bf16.h>
#include <math.h>
#include <stddef.h>

// Problem constants (from reference)
#define NB 8
#define NT 1024
#define NF 80
#define NSTACK 4
#define NSTRIDE 4
#define NG 4
#define NE 16
#define NC 8192
#define ND 512
#define NTS 256          // (NT-NSTACK)/NSTRIDE + 1
#define NP (NB*NTS)      // 2048 subsampled positions
#define SFD (NSTACK*NF)  // 320
#define FREG 0.01f
#define LNEPS 1e-5f

// fp32-fallback k_logits tiling
#define TCC 1024
#define CPT 4
#define PCH 16
#define PB 16

// MFMA path
#define ROWS_MAX 2176     // >= ceil(2048/144)*144 = 2160
#define ROWCH 144         // rows per chunk (all in acc regs, W read once)
#define MT 9              // 16-row m-tiles per chunk
#define QCH 128           // lat rows staged per k_qdist pass
#define CT 128            // c-tiles of 64 for the logits GEMM partials
#define QS 8              // qdist atomic spread slots

typedef __attribute__((ext_vector_type(8))) short short8;
typedef __attribute__((ext_vector_type(4))) float f32x4;

struct Ws {
  // ---------- zero-initialized region (memset) ----------
  float penSum;
  unsigned int nA;
  unsigned int maskIsInt;
  unsigned int pad1;
  unsigned long long amax[NP*NG];   // final packed (key<<32 | ~idx) argmax
  float sumExp[NP*NG];
  float tLogit[NP*NG];
  int   targets[NP*NG];
  int   activeList[NP];
  unsigned int bitmap[NC/32];
  // ---------- initialized by k_prologue ----------
  unsigned long long aminS[NP*NG*QS]; // qdist spread argmin slots (0xFF)
  // ---------- no init needed ----------
  float lat[NP][64];
  // fragment-order bf16 splits of active encoder rows:
  // aHiT[((k/8)*ROWS_MAX + row)*8 + (k%8)]
  unsigned short aHiT[(size_t)(ND/8)*ROWS_MAX*8];
  unsigned short aLoT[(size_t)(ND/8)*ROWS_MAX*8];
  float part_se[NG][ROWS_MAX][CT];
  unsigned long long part_mx[NG][ROWS_MAX][CT];
};

__device__ inline unsigned short bf16_rne(float x) {
  unsigned u = __float_as_uint(x);
  unsigned r = u + 0x7FFFu + ((u >> 16) & 1u);
  return (unsigned short)(r >> 16);
}
__device__ inline unsigned fkey_asc(float d) {  // ascending float -> ascending uint
  unsigned u = __float_as_uint(d);
  return (u & 0x80000000u) ? ~u : (u | 0x80000000u);
}

// ---- fused prologue: features_pen + mask/compact + aminS init ----
__global__ __launch_bounds__(256) void k_prologue(
    const float* __restrict__ feats, const float* __restrict__ mean,
    const float* __restrict__ istd, const unsigned char* __restrict__ m8,
    const int* __restrict__ lens, int doClear, Ws* ws) {
  const int tid = threadIdx.x;
  if (doClear) ws->aminS[(size_t)blockIdx.x*256 + tid] = ~0ull;

  const int N4 = NB*NT*NF/4;
  float s = 0.f;
  for (int i = blockIdx.x*256 + tid; i < N4; i += gridDim.x*256) {
    float4 v = reinterpret_cast<const float4*>(feats)[i];
    int f0 = (i*4) % NF;
    float x0 = (v.x - mean[f0+0]) * istd[f0+0];
    float x1 = (v.y - mean[f0+1]) * istd[f0+1];
    float x2 = (v.z - mean[f0+2]) * istd[f0+2];
    float x3 = (v.w - mean[f0+3]) * istd[f0+3];
    s += x0*x0 + x1*x1 + x2*x2 + x3*x3;
  }
  for (int o = 32; o; o >>= 1) s += __shfl_down(s, o);
  __shared__ float pr[4];
  if ((tid & 63) == 0) pr[tid >> 6] = s;
  __syncthreads();
  if (tid == 0) atomicAdd(&ws->penSum, pr[0]+pr[1]+pr[2]+pr[3]);

  if (blockIdx.x < NP/256) {
    __shared__ unsigned flag;
    if (tid == 0) flag = 0;
    __syncthreads();
    unsigned nz = 0;
    int base = tid * 32;
    for (int i = base; i < base + 32; ++i)
      if ((i & 3) && m8[i]) nz = 1;
    if (nz) atomicOr(&flag, 1u);
    __syncthreads();
    bool isInt = (flag == 0);

    int p = blockIdx.x*256 + tid;
    int b = p >> 8, ts = p & (NTS-1);
    int t0 = b*NT + ts*NSTRIDE;
    bool allm;
    if (isInt) {
      const int* m32 = (const int*)m8;
      allm = m32[t0] && m32[t0+1] && m32[t0+2] && m32[t0+3];
    } else {
      allm = m8[t0] && m8[t0+1] && m8[t0+2] && m8[t0+3];
    }
    int ls = (lens[b] - NSTACK)/NSTRIDE + 1;
    if (ls < 0) ls = 0;
    if (allm && ts < ls) {
      unsigned idx = atomicAdd(&ws->nA, 1u);
      ws->activeList[idx] = p;
    }
  }
}

// ---- fused: latents (stack+LN+proj) AND fragment-order enc bf16 split ----
__global__ __launch_bounds__(256) void k_latprep(
    const float* __restrict__ feats, const float* __restrict__ mean,
    const float* __restrict__ istd, const float* __restrict__ projw,
    const float* __restrict__ enc, Ws* ws) {
  int nA = (int)ws->nA;
  int ai = blockIdx.x;
  int limit = ((nA + ROWCH - 1) / ROWCH) * ROWCH;
  int tid = threadIdx.x;

  if (ai >= nA) {
    if (ai < limit && tid < 64) {     // zero-pad fragment rows
      short8 z;
      #pragma unroll
      for (int j = 0; j < 8; ++j) z[j] = 0;
      *reinterpret_cast<short8*>(ws->aHiT + ((size_t)tid*ROWS_MAX + ai)*8) = z;
      *reinterpret_cast<short8*>(ws->aLoT + ((size_t)tid*ROWS_MAX + ai)*8) = z;
    }
    return;
  }

  int p = ws->activeList[ai];
  if (tid < 64) {
    const float* src = enc + (size_t)p*ND + tid*8;
    float4 x0 = *reinterpret_cast<const float4*>(src);
    float4 x1 = *reinterpret_cast<const float4*>(src + 4);
    float xv[8] = {x0.x, x0.y, x0.z, x0.w, x1.x, x1.y, x1.z, x1.w};
    short8 h, l;
    #pragma unroll
    for (int j = 0; j < 8; ++j) {
      unsigned short hi = bf16_rne(xv[j]);
      float rem = xv[j] - __uint_as_float((unsigned)hi << 16);
      h[j] = (short)hi;
      l[j] = (short)bf16_rne(rem);
    }
    *reinterpret_cast<short8*>(ws->aHiT + ((size_t)tid*ROWS_MAX + ai)*8) = h;
    *reinterpret_cast<short8*>(ws->aLoT + ((size_t)tid*ROWS_MAX + ai)*8) = l;
  }

  int b = p >> 8, ts = p & (NTS-1);
  __shared__ float sN[SFD];
  __shared__ float sPart[4*64];
  __shared__ float rS[4], rQ[4];

  for (int j = tid; j < SFD; j += 256) {
    int k = j / NF, f = j - k*NF;
    sN[j] = (feats[((size_t)b*NT + ts*NSTRIDE + k)*NF + f] - mean[f]) * istd[f];
  }
  __syncthreads();
  float s = 0.f, q = 0.f;
  for (int j = tid; j < SFD; j += 256) { float x = sN[j]; s += x; q += x*x; }
  for (int o = 32; o; o >>= 1) { s += __shfl_down(s, o); q += __shfl_down(q, o); }
  if ((tid & 63) == 0) { rS[tid>>6] = s; rQ[tid>>6] = q; }
  __syncthreads();
  float mu  = (rS[0]+rS[1]+rS[2]+rS[3]) * (1.f/SFD);
  float var = (rQ[0]+rQ[1]+rQ[2]+rQ[3]) * (1.f/SFD) - mu*mu;
  float inv = rsqrtf(var + LNEPS);
  for (int j = tid; j < SFD; j += 256) sN[j] = (sN[j]-mu)*inv;
  __syncthreads();
  {
    int j = tid & 63, part = tid >> 6;
    float a = 0.f;
    int i0 = part*80;
    for (int i = i0; i < i0+80; ++i) a = fmaf(sN[i], projw[i*64 + j], a);
    sPart[part*64 + j] = a;
  }
  __syncthreads();
  if (tid < 64)
    ws->lat[ai][tid] = sPart[tid] + sPart[64+tid] + sPart[128+tid] + sPart[192+tid];
}

// ---- codebook argmin, c-parallel; spread atomicMin (8 slots) ----
__global__ __launch_bounds__(256) void k_qdist(const float* __restrict__ emb, Ws* ws) {
  int nA = (int)ws->nA;
  if (nA == 0) return;
  int tid = threadIdx.x;
  int g = tid >> 6, lane = tid & 63;
  int c = blockIdx.x * 64 + lane;
  int per = (nA + 1) >> 1;
  int a0 = blockIdx.y * per;
  int a1 = min(nA, a0 + per);
  int slot = blockIdx.x & (QS-1);

  const float4* e4 = reinterpret_cast<const float4*>(emb + ((size_t)c*NG + g)*NE);
  float4 b0 = e4[0], b1 = e4[1], b2 = e4[2], b3 = e4[3];
  float n2 = b0.x*b0.x + b0.y*b0.y + b0.z*b0.z + b0.w*b0.w
           + b1.x*b1.x + b1.y*b1.y + b1.z*b1.z + b1.w*b1.w
           + b2.x*b2.x + b2.y*b2.y + b2.z*b2.z + b2.w*b2.w
           + b3.x*b3.x + b3.y*b3.y + b3.z*b3.z + b3.w*b3.w;

  __shared__ float sL[QCH][64];
  for (int base = a0; base < a1; base += QCH) {
    int cnt = min(QCH, a1 - base);
    __syncthreads();
    for (int i = tid; i < cnt*64; i += 256)
      (&sL[0][0])[i] = (&ws->lat[0][0])[(size_t)(base + (i >> 6))*64 + (i & 63)];
    __syncthreads();
    for (int i = 0; i < cnt; ++i) {
      const float* lp = &sL[i][g*NE];
      float dot = lp[0]*b0.x + lp[1]*b0.y + lp[2]*b0.z + lp[3]*b0.w
                + lp[4]*b1.x + lp[5]*b1.y + lp[6]*b1.z + lp[7]*b1.w
                + lp[8]*b2.x + lp[9]*b2.y + lp[10]*b2.z + lp[11]*b2.w
                + lp[12]*b3.x + lp[13]*b3.y + lp[14]*b3.z + lp[15]*b3.w;
      float d = n2 - 2.f*dot;
      float mv = d; int mc = c;
      #pragma unroll
      for (int off = 32; off; off >>= 1) {
        float ov = __shfl_xor(mv, off);
        int   oc = __shfl_xor(mc, off);
        if (ov < mv || (ov == mv && oc < mc)) { mv = ov; mc = oc; }
      }
      if (lane == 0) {
        unsigned long long key =
            ((unsigned long long)fkey_asc(mv) << 32) | (unsigned)mc;
        atomicMin(&ws->aminS[(size_t)((base + i)*NG + g)*QS + slot], key);
      }
    }
  }
}

// ---- extract targets + uniq bitmap from spread slots ----
__global__ void k_tgt(Ws* ws) {
  int i = blockIdx.x*256 + threadIdx.x;
  int nA = (int)ws->nA;
  if (i < nA*NG) {
    unsigned long long m = ws->aminS[(size_t)i*QS];
    #pragma unroll
    for (int s = 1; s < QS; ++s) {
      unsigned long long v = ws->aminS[(size_t)i*QS + s];
      if (v < m) m = v;
    }
    int c = (int)(unsigned)(m & 0xFFFFFFFFull);
    ws->targets[i] = c;
    atomicOr(&ws->bitmap[c >> 5], 1u << (c & 31));
  }
}

// ---- logits GEMM: W read+split exactly once (A-operand), enc fragment-order
// (B-operand), in-block K-split across waves for TLP, atomic-free epilogue ----
// block = 512 threads = 8 waves: sub = wave&3 (c-16 sub-tile), kh = wave>>2
// (k-half). K-halves combine through LDS; epilogue on kh==0 waves.
__global__ __launch_bounds__(512, 4) void k_logits_mfma(
    const float* __restrict__ W, const float* __restrict__ bias, Ws* ws) {
  const int nA = (int)ws->nA;
  if (nA == 0) return;
  const int nCh = (nA + ROWCH - 1) / ROWCH;
  const int tid = threadIdx.x;
  const int wave = tid >> 6, lane = tid & 63;
  const int sub = wave & 3, kh = wave >> 2;
  const int g = blockIdx.y;
  const int c0w = blockIdx.x * 64 + sub * 16;
  const int lo16 = lane & 15, hi4 = lane >> 4;
  const int cA = c0w + lo16;           // A-fragment column
  const int cOut0 = c0w + hi4*4;       // this lane's 4 output c's
  float bv[4];
  #pragma unroll
  for (int v = 0; v < 4; ++v) bv[v] = bias[g*NC + cOut0 + v];

  __shared__ f32x4 sAcc[4][MT][64];              // 36 KB k-half combine
  __shared__ float sEs[4][ROWCH];
  __shared__ unsigned long long sMx[4][ROWCH];

  for (int ch = 0; ch < nCh; ++ch) {
    const int r0 = ch * ROWCH;
    f32x4 acc[MT];
    #pragma unroll
    for (int mt = 0; mt < MT; ++mt) acc[mt] = (f32x4){0.f, 0.f, 0.f, 0.f};

    for (int ks = kh*8; ks < kh*8 + 8; ++ks) {
      // B fragments: contiguous 256B per 16-lane group, L1/L2-resident
      short8 bh[MT], bl[MT];
      const size_t boff = ((size_t)(ks*4 + hi4)*ROWS_MAX + r0 + lo16)*8;
      #pragma unroll
      for (int mt = 0; mt < MT; ++mt) {
        bh[mt] = *reinterpret_cast<const short8*>(ws->aHiT + boff + (size_t)mt*128);
        bl[mt] = *reinterpret_cast<const short8*>(ws->aLoT + boff + (size_t)mt*128);
      }
      // A fragment: W[k][c], 4x64B contiguous segments per load; each W
      // element touched exactly once chip-wide
      const float* wp = W + ((size_t)g*ND + ks*32 + hi4*8)*NC + cA;
      float wv[8];
      #pragma unroll
      for (int j = 0; j < 8; ++j) wv[j] = wp[(size_t)j*NC];
      short8 whi, wlo;
      #pragma unroll
      for (int j = 0; j < 8; ++j) {
        unsigned short h = bf16_rne(wv[j]);
        float rem = wv[j] - __uint_as_float((unsigned)h << 16);
        whi[j] = (short)h;
        wlo[j] = (short)bf16_rne(rem);
      }
      #pragma unroll
      for (int mt = 0; mt < MT; ++mt) {
        acc[mt] = __builtin_amdgcn_mfma_f32_16x16x32_bf16(whi, bh[mt], acc[mt], 0, 0, 0);
        acc[mt] = __builtin_amdgcn_mfma_f32_16x16x32_bf16(wlo, bh[mt], acc[mt], 0, 0, 0);
        acc[mt] = __builtin_amdgcn_mfma_f32_16x16x32_bf16(whi, bl[mt], acc[mt], 0, 0, 0);
      }
    }

    // ---- combine k-halves through LDS ----
    if (kh == 1) {
      #pragma unroll
      for (int mt = 0; mt < MT; ++mt) sAcc[sub][mt][lane] = acc[mt];
    }
    __syncthreads();

    if (kh == 0) {
      // epilogue: D[m=c-local=(hi4*4+v)][n=row=lo16]
      #pragma unroll
      for (int mt = 0; mt < MT; ++mt) {
        f32x4 oth = sAcc[sub][mt][lane];
        const int row = r0 + mt*16 + lo16;
        const int tgt = (row < nA) ? ws->targets[row*NG + g] : -1;
        float lv[4];
        #pragma unroll
        for (int v = 0; v < 4; ++v) lv[v] = (acc[mt][v] + oth[v]) + bv[v];
        #pragma unroll
        for (int v = 0; v < 4; ++v)
          if (tgt == cOut0 + v) ws->tLogit[row*NG + g] = lv[v];
        float es = expf(lv[0]) + expf(lv[1]) + expf(lv[2]) + expf(lv[3]);
        float mv = lv[0]; int mi = cOut0;
        if (lv[1] > mv) { mv = lv[1]; mi = cOut0+1; }
        if (lv[2] > mv) { mv = lv[2]; mi = cOut0+2; }
        if (lv[3] > mv) { mv = lv[3]; mi = cOut0+3; }
        #pragma unroll
        for (int off = 16; off <= 32; off <<= 1) {
          es += __shfl_xor(es, off);
          float ov = __shfl_xor(mv, off);
          int   oi = __shfl_xor(mi, off);
          if (ov > mv || (ov == mv && oi < mi)) { mv = ov; mi = oi; }
        }
        if (hi4 == 0) {
          sEs[sub][mt*16 + lo16] = es;
          unsigned key = __float_as_uint(mv);
          key = (key & 0x80000000u) ? ~key : (key | 0x80000000u);
          sMx[sub][mt*16 + lo16] = ((unsigned long long)key << 32)
                                 | (unsigned long long)(0xFFFFFFFFu - (unsigned)mi);
        }
      }
    }
    __syncthreads();
    if (tid < ROWCH) {
      float e = sEs[0][tid] + sEs[1][tid] + sEs[2][tid] + sEs[3][tid];
      unsigned long long m0 = sMx[0][tid], m1 = sMx[1][tid];
      unsigned long long m2 = sMx[2][tid], m3 = sMx[3][tid];
      unsigned long long ma = m0 > m1 ? m0 : m1;
      unsigned long long mb = m2 > m3 ? m2 : m3;
      unsigned long long mx = ma > mb ? ma : mb;
      int grow = r0 + tid;
      ws->part_se[g][grow][blockIdx.x] = e;
      ws->part_mx[g][grow][blockIdx.x] = mx;
    }
    __syncthreads();
  }
}

// ---- reduce 128 c-tile partials per (row,g): plain stores, no atomics ----
__global__ __launch_bounds__(256) void k_red_l(Ws* ws) {
  int nA = (int)ws->nA;
  int pair = blockIdx.x*4 + (threadIdx.x >> 6);
  int lane = threadIdx.x & 63;
  int row = pair >> 2, g = pair & 3;
  if (row >= nA) return;
  float e = ws->part_se[g][row][lane] + ws->part_se[g][row][lane + 64];
  unsigned long long a = ws->part_mx[g][row][lane];
  unsigned long long b = ws->part_mx[g][row][lane + 64];
  unsigned long long mx = a > b ? a : b;
  #pragma unroll
  for (int off = 32; off; off >>= 1) {
    e += __shfl_xor(e, off);
    unsigned long long o = __shfl_xor(mx, off);
    if (o > mx) mx = o;
  }
  if (lane == 0) {
    ws->sumExp[row*NG + g] = e;
    ws->amax[row*NG + g] = mx;
  }
}

// ======================= fallback fp32 path (round-1, proven) ==============
__global__ __launch_bounds__(256) void k_quant(
    const float* __restrict__ feats, const float* __restrict__ mean,
    const float* __restrict__ istd, const float* __restrict__ projw,
    const float* __restrict__ emb, Ws* ws) {
  if (blockIdx.x >= ws->nA) return;
  int ai = blockIdx.x;
  int p = ws->activeList[ai];
  int b = p >> 8, ts = p & (NTS-1);
  int tid = threadIdx.x;
  __shared__ float sN[SFD];
  __shared__ float sPart[4*64];
  __shared__ float sLat[NG*NE];
  __shared__ float sRedS[256];
  __shared__ int   sRedC[256];
  __shared__ float rS[4], rQ[4];
  __shared__ int   sTgt[NG];

  for (int j = tid; j < SFD; j += 256) {
    int k = j / NF, f = j - k*NF;
    sN[j] = (feats[((size_t)b*NT + ts*NSTRIDE + k)*NF + f] - mean[f]) * istd[f];
  }
  __syncthreads();
  float s = 0.f, q = 0.f;
  for (int j = tid; j < SFD; j += 256) { float x = sN[j]; s += x; q += x*x; }
  for (int o = 32; o; o >>= 1) { s += __shfl_down(s, o); q += __shfl_down(q, o); }
  if ((tid & 63) == 0) { rS[tid>>6] = s; rQ[tid>>6] = q; }
  __syncthreads();
  float mu  = (rS[0]+rS[1]+rS[2]+rS[3]) * (1.f/SFD);
  float var = (rQ[0]+rQ[1]+rQ[2]+rQ[3]) * (1.f/SFD) - mu*mu;
  float inv = rsqrtf(var + LNEPS);
  for (int j = tid; j < SFD; j += 256) sN[j] = (sN[j]-mu)*inv;
  __syncthreads();
  {
    int j = tid & 63, part = tid >> 6;
    float a = 0.f;
    int i0 = part*80;
    for (int i = i0; i < i0+80; ++i) a = fmaf(sN[i], projw[i*64 + j], a);
    sPart[part*64 + j] = a;
  }
  __syncthreads();
  if (tid < 64) sLat[tid] = sPart[tid] + sPart[64+tid] + sPart[128+tid] + sPart[192+tid];
  __syncthreads();

  for (int gg = 0; gg < NG; ++gg) {
    float lg[NE];
    #pragma unroll
    for (int e = 0; e < NE; ++e) lg[e] = sLat[gg*NE + e];
    float best = 3.4e38f; int bc = NC;
    for (int c = tid; c < NC; c += 256) {
      const float4* cb4 = reinterpret_cast<const float4*>(emb + ((size_t)c*NG + gg)*NE);
      float4 a0 = cb4[0], a1 = cb4[1], a2 = cb4[2], a3 = cb4[3];
      float dot = 0.f, n2 = 0.f;
      dot = fmaf(lg[0],  a0.x, dot); n2 = fmaf(a0.x, a0.x, n2);
      dot = fmaf(lg[1],  a0.y, dot); n2 = fmaf(a0.y, a0.y, n2);
      dot = fmaf(lg[2],  a0.z, dot); n2 = fmaf(a0.z, a0.z, n2);
      dot = fmaf(lg[3],  a0.w, dot); n2 = fmaf(a0.w, a0.w, n2);
      dot = fmaf(lg[4],  a1.x, dot); n2 = fmaf(a1.x, a1.x, n2);
      dot = fmaf(lg[5],  a1.y, dot); n2 = fmaf(a1.y, a1.y, n2);
      dot = fmaf(lg[6],  a1.z, dot); n2 = fmaf(a1.z, a1.z, n2);
      dot = fmaf(lg[7],  a1.w, dot); n2 = fmaf(a1.w, a1.w, n2);
      dot = fmaf(lg[8],  a2.x, dot); n2 = fmaf(a2.x, a2.x, n2);
      dot = fmaf(lg[9],  a2.y, dot); n2 = fmaf(a2.y, a2.y, n2);
      dot = fmaf(lg[10], a2.z, dot); n2 = fmaf(a2.z, a2.z, n2);
      dot = fmaf(lg[11], a2.w, dot); n2 = fmaf(a2.w, a2.w, n2);
      dot = fmaf(lg[12], a3.x, dot); n2 = fmaf(a3.x, a3.x, n2);
      dot = fmaf(lg[13], a3.y, dot); n2 = fmaf(a3.y, a3.y, n2);
      dot = fmaf(lg[14], a3.z, dot); n2 = fmaf(a3.z, a3.z, n2);
      dot = fmaf(lg[15], a3.w, dot); n2 = fmaf(a3.w, a3.w, n2);
      float sc = n2 - 2.f*dot;
      if (sc < best) { best = sc; bc = c; }
    }
    sRedS[tid] = best; sRedC[tid] = bc;
    __syncthreads();
    for (int off = 128; off; off >>= 1) {
      if (tid < off) {
        float os = sRedS[tid+off]; int oc = sRedC[tid+off];
        if (os < sRedS[tid] || (os == sRedS[tid] && oc < sRedC[tid])) {
          sRedS[tid] = os; sRedC[tid] = oc;
        }
      }
      __syncthreads();
    }
    if (tid == 0) sTgt[gg] = sRedC[0];
    __syncthreads();
  }
  if (tid < NG) {
    int c = sTgt[tid];
    ws->targets[ai*NG + tid] = c;
    atomicOr(&ws->bitmap[c >> 5], 1u << (c & 31));
  }
}

__global__ __launch_bounds__(256) void k_logits(
    const float* __restrict__ W, const float* __restrict__ bias,
    const float* __restrict__ enc, Ws* ws) {
  const int nA = (int)ws->nA;
  if (nA == 0) return;
  const int nCh = (nA + PCH - 1) / PCH;
  const int g = blockIdx.y;
  const int cbase = blockIdx.x * TCC + threadIdx.x * CPT;
  const float* __restrict__ Wg = W + (size_t)g*ND*NC;
  const float b0 = bias[g*NC + cbase + 0];
  const float b1 = bias[g*NC + cbase + 1];
  const float b2 = bias[g*NC + cbase + 2];
  const float b3 = bias[g*NC + cbase + 3];
  __shared__ float4 sEnc[PCH][ND/4];
  __shared__ int sP[PCH];

  for (int ch = blockIdx.z; ch < nCh; ch += PB) {
    if (threadIdx.x < PCH) {
      int ai = ch*PCH + threadIdx.x;
      sP[threadIdx.x] = (ai < nA) ? ws->activeList[ai] : -1;
    }
    __syncthreads();
    for (int i = threadIdx.x; i < PCH*(ND/4); i += 256) {
      int qq = i >> 7, r = i & 127;
      int p = sP[qq];
      sEnc[qq][r] = (p >= 0) ? reinterpret_cast<const float4*>(enc)[p*(ND/4) + r]
                             : make_float4(0.f, 0.f, 0.f, 0.f);
    }
    __syncthreads();

    float acc[PCH][CPT];
    #pragma unroll
    for (int qq = 0; qq < PCH; ++qq)
      #pragma unroll
      for (int j = 0; j < CPT; ++j) acc[qq][j] = 0.f;
    for (int d = 0; d < ND; d += 4) {
      const float* wp = Wg + (size_t)d*NC + cbase;
      float4 w0 = *reinterpret_cast<const float4*>(wp);
      float4 w1 = *reinterpret_cast<const float4*>(wp + NC);
      float4 w2 = *reinterpret_cast<const float4*>(wp + 2*NC);
      float4 w3 = *reinterpret_cast<const float4*>(wp + 3*NC);
      int dq = d >> 2;
      #pragma unroll
      for (int qq = 0; qq < PCH; ++qq) {
        float4 e = sEnc[qq][dq];
        acc[qq][0] = fmaf(e.x, w0.x, acc[qq][0]);
        acc[qq][1] = fmaf(e.x, w0.y, acc[qq][1]);
        acc[qq][2] = fmaf(e.x, w0.z, acc[qq][2]);
        acc[qq][3] = fmaf(e.x, w0.w, acc[qq][3]);
        acc[qq][0] = fmaf(e.y, w1.x, acc[qq][0]);
        acc[qq][1] = fmaf(e.y, w1.y, acc[qq][1]);
        acc[qq][2] = fmaf(e.y, w1.z, acc[qq][2]);
        acc[qq][3] = fmaf(e.y, w1.w, acc[qq][3]);
        acc[qq][0] = fmaf(e.z, w2.x, acc[qq][0]);
        acc[qq][1] = fmaf(e.z, w2.y, acc[qq][1]);
        acc[qq][2] = fmaf(e.z, w2.z, acc[qq][2]);
        acc[qq][3] = fmaf(e.z, w2.w, acc[qq][3]);
        acc[qq][0] = fmaf(e.w, w3.x, acc[qq][0]);
        acc[qq][1] = fmaf(e.w, w3.y, acc[qq][1]);
        acc[qq][2] = fmaf(e.w, w3.z, acc[qq][2]);
        acc[qq][3] = fmaf(e.w, w3.w, acc[qq][3]);
      }
    }

    #pragma unroll
    for (int qq = 0; qq < PCH; ++qq) {
      int ai = ch*PCH + qq;
      if (ai < nA) {
        float l0 = acc[qq][0] + b0;
        float l1 = acc[qq][1] + b1;
        float l2 = acc[qq][2] + b2;
        float l3 = acc[qq][3] + b3;
        int tgt = ws->targets[ai*NG + g];
        if ((unsigned)(tgt - cbase) < (unsigned)CPT) {
          float tv = (tgt == cbase) ? l0 : (tgt == cbase+1) ? l1
                   : (tgt == cbase+2) ? l2 : l3;
          ws->tLogit[ai*NG + g] = tv;
        }
        float es = expf(l0) + expf(l1) + expf(l2) + expf(l3);
        float mv = l0; int mi = cbase;
        if (l1 > mv) { mv = l1; mi = cbase+1; }
        if (l2 > mv) { mv = l2; mi = cbase+2; }
        if (l3 > mv) { mv = l3; mi = cbase+3; }
        for (int o = 32; o; o >>= 1) {
          es += __shfl_down(es, o);
          float ov = __shfl_down(mv, o);
          int   oi = __shfl_down(mi, o);
          if (ov > mv || (ov == mv && oi < mi)) { mv = ov; mi = oi; }
        }
        if ((threadIdx.x & 63) == 0) {
          atomicAdd(&ws->sumExp[ai*NG + g], es);
          unsigned key = __float_as_uint(mv);
          key = (key & 0x80000000u) ? ~key : (key | 0x80000000u);
          unsigned long long pk =
              ((unsigned long long)key << 32) |
              (unsigned long long)(0xFFFFFFFFu - (unsigned)mi);
          atomicMax(&ws->amax[ai*NG + g], pk);
        }
      }
    }
    __syncthreads();
  }
}
// ======================= end fallback =======================================

// ---- final scalar assembly ----
__global__ __launch_bounds__(256) void k_final(Ws* ws, float* __restrict__ out) {
  int tid = threadIdx.x;
  int nA = (int)ws->nA;
  float sumPer = 0.f, sumCorr = 0.f;
  for (int i = tid; i < nA*NG; i += 256) {
    sumPer += logf(ws->sumExp[i]) - ws->tLogit[i];
    unsigned long long pk = ws->amax[i];
    int mi = (int)(0xFFFFFFFFu - (unsigned)(pk & 0xFFFFFFFFull));
    if (mi == ws->targets[i]) sumCorr += 1.f;
  }
  unsigned w = ws->bitmap[tid];
  if (tid == 0 && nA < NP) w |= 1u;
  int uniq = __popc(w);

  __shared__ float rs[4], rc[4]; __shared__ int ru[4];
  float s1 = sumPer, s2 = sumCorr; int s3 = uniq;
  for (int o = 32; o; o >>= 1) {
    s1 += __shfl_down(s1, o);
    s2 += __shfl_down(s2, o);
    s3 += __shfl_down(s3, o);
  }
  if ((tid & 63) == 0) { rs[tid>>6] = s1; rc[tid>>6] = s2; ru[tid>>6] = s3; }
  __syncthreads();
  if (tid == 0) {
    float sp = rs[0]+rs[1]+rs[2]+rs[3];
    float sc = rc[0]+rc[1]+rc[2]+rc[3];
    int   un = ru[0]+ru[1]+ru[2]+ru[3];
    float pen   = ws->penSum / (float)(NB*NT*NF);
    float denom = (float)nA + 1e-5f;
    float nc    = (float)(nA * NG);
    out[0] = sp / (denom * (float)NG) + FREG * pen;
    out[1] = sc / nc;
    out[2] = pen;
    out[3] = nc;
    out[4] = (float)un;
  }
}

extern "C" void kernel_launch(void* const* d_in, const int* in_sizes, int n_in,
                              void* d_out, int out_size, void* d_ws, size_t ws_size,
                              hipStream_t stream) {
  const float* feats = (const float*)d_in[0];
  const int*   lens  = (const int*)d_in[1];
  const unsigned char* masks = (const unsigned char*)d_in[2];
  const float* mean  = (const float*)d_in[4];
  const float* istd  = (const float*)d_in[5];
  const float* projw = (const float*)d_in[6];
  const float* emb   = (const float*)d_in[7];
  const float* W     = (const float*)d_in[8];
  const float* bias  = (const float*)d_in[9];
  const float* enc   = (const float*)d_in[10];
  Ws* ws = (Ws*)d_ws;
  float* out = (float*)d_out;

  bool big = ws_size >= sizeof(Ws);
  size_t zr = offsetof(Ws, aminS);
  hipMemsetAsync(d_ws, 0, (big || ws_size >= zr) ? zr : ws_size, stream);

  k_prologue<<<256, 256, 0, stream>>>(feats, mean, istd, masks, lens,
                                      big ? 1 : 0, ws);

  if (big) {
    k_latprep<<<ROWS_MAX, 256, 0, stream>>>(feats, mean, istd, projw, enc, ws);
    k_qdist<<<dim3(NC/64, 2), 256, 0, stream>>>(emb, ws);
    k_tgt<<<NP*NG/256, 256, 0, stream>>>(ws);
    k_logits_mfma<<<dim3(CT, NG), 512, 0, stream>>>(W, bias, ws);
    k_red_l<<<NP, 256, 0, stream>>>(ws);
  } else {
    k_quant<<<NP, 256, 0, stream>>>(feats, mean, istd, projw, emb, ws);
    k_logits<<<dim3(NC/TCC, NG, PB), 256, 0, stream>>>(W, bias, enc, ws);
  }
  k_final<<<1, 256, 0, stream>>>(ws, out);
}

// Round 7
// 83.305 us; speedup vs baseline: 7.8561x; 1.3369x over previous
//
#include <hip/hip_runtime.h>
#include <hip/hip_bf16.h>
#include <math.h>
#include <stddef.h>

// Problem constants (from reference)
#define NB 8
#define NT 1024
#define NF 80
#define NSTACK 4
#define NSTRIDE 4
#define NG 4
#define NE 16
#define NC 8192
#define ND 512
#define NTS 256          // (NT-NSTACK)/NSTRIDE + 1
#define NP (NB*NTS)      // 2048 subsampled positions
#define SFD (NSTACK*NF)  // 320
#define FREG 0.01f
#define LNEPS 1e-5f

// fp32-fallback k_logits tiling
#define TCC 1024
#define CPT 4
#define PCH 16
#define PB 16

// MFMA path
#define ROWS_MAX 2176     // >= ceil(2048/144)*144 = 2160
#define ROWCH 144         // rows per chunk (all in acc regs, W read once)
#define MT 9              // 16-row m-tiles per chunk
#define QCH 16            // lat rows staged per k_qdist pass (4 KB LDS)
#define QY 16             // k_qdist row-split factor (grid.y)
#define CT 128            // c-tiles of 64 for the logits GEMM partials
#define QS 8              // qdist atomic spread slots

typedef __attribute__((ext_vector_type(8))) short short8;
typedef __attribute__((ext_vector_type(4))) float f32x4;

struct Ws {
  // ---------- zero-initialized region (memset) ----------
  float penSum;
  unsigned int nA;
  unsigned int maskIsInt;
  unsigned int pad1;
  unsigned long long amax[NP*NG];   // final packed (key<<32 | ~idx) argmax
  float sumExp[NP*NG];
  float tLogit[NP*NG];
  int   targets[NP*NG];
  int   activeList[NP];
  unsigned int bitmap[NC/32];
  // ---------- initialized by k_prologue ----------
  unsigned long long aminS[NP*NG*QS]; // qdist spread argmin slots (0xFF)
  // ---------- no init needed ----------
  float lat[NP][64];
  // fragment-order bf16 splits of active encoder rows:
  // aHiT[((k/8)*ROWS_MAX + row)*8 + (k%8)]
  unsigned short aHiT[(size_t)(ND/8)*ROWS_MAX*8];
  unsigned short aLoT[(size_t)(ND/8)*ROWS_MAX*8];
  float part_se[NG][ROWS_MAX][CT];
  unsigned long long part_mx[NG][ROWS_MAX][CT];
};

__device__ inline unsigned short bf16_rne(float x) {
  unsigned u = __float_as_uint(x);
  unsigned r = u + 0x7FFFu + ((u >> 16) & 1u);
  return (unsigned short)(r >> 16);
}
__device__ inline unsigned fkey_asc(float d) {  // ascending float -> ascending uint
  unsigned u = __float_as_uint(d);
  return (u & 0x80000000u) ? ~u : (u | 0x80000000u);
}

// ---- fused prologue: features_pen + mask/compact + aminS init ----
__global__ __launch_bounds__(256) void k_prologue(
    const float* __restrict__ feats, const float* __restrict__ mean,
    const float* __restrict__ istd, const unsigned char* __restrict__ m8,
    const int* __restrict__ lens, int doClear, Ws* ws) {
  const int tid = threadIdx.x;
  if (doClear) ws->aminS[(size_t)blockIdx.x*256 + tid] = ~0ull;

  const int N4 = NB*NT*NF/4;
  float s = 0.f;
  for (int i = blockIdx.x*256 + tid; i < N4; i += gridDim.x*256) {
    float4 v = reinterpret_cast<const float4*>(feats)[i];
    int f0 = (i*4) % NF;
    float x0 = (v.x - mean[f0+0]) * istd[f0+0];
    float x1 = (v.y - mean[f0+1]) * istd[f0+1];
    float x2 = (v.z - mean[f0+2]) * istd[f0+2];
    float x3 = (v.w - mean[f0+3]) * istd[f0+3];
    s += x0*x0 + x1*x1 + x2*x2 + x3*x3;
  }
  for (int o = 32; o; o >>= 1) s += __shfl_down(s, o);
  __shared__ float pr[4];
  if ((tid & 63) == 0) pr[tid >> 6] = s;
  __syncthreads();
  if (tid == 0) atomicAdd(&ws->penSum, pr[0]+pr[1]+pr[2]+pr[3]);

  if (blockIdx.x < NP/256) {
    __shared__ unsigned flag;
    if (tid == 0) flag = 0;
    __syncthreads();
    unsigned nz = 0;
    int base = tid * 32;
    for (int i = base; i < base + 32; ++i)
      if ((i & 3) && m8[i]) nz = 1;
    if (nz) atomicOr(&flag, 1u);
    __syncthreads();
    bool isInt = (flag == 0);

    int p = blockIdx.x*256 + tid;
    int b = p >> 8, ts = p & (NTS-1);
    int t0 = b*NT + ts*NSTRIDE;
    bool allm;
    if (isInt) {
      const int* m32 = (const int*)m8;
      allm = m32[t0] && m32[t0+1] && m32[t0+2] && m32[t0+3];
    } else {
      allm = m8[t0] && m8[t0+1] && m8[t0+2] && m8[t0+3];
    }
    int ls = (lens[b] - NSTACK)/NSTRIDE + 1;
    if (ls < 0) ls = 0;
    if (allm && ts < ls) {
      unsigned idx = atomicAdd(&ws->nA, 1u);
      ws->activeList[idx] = p;
    }
  }
}

// ---- fused: latents (stack+LN+proj) AND fragment-order enc bf16 split ----
__global__ __launch_bounds__(256) void k_latprep(
    const float* __restrict__ feats, const float* __restrict__ mean,
    const float* __restrict__ istd, const float* __restrict__ projw,
    const float* __restrict__ enc, Ws* ws) {
  int nA = (int)ws->nA;
  int ai = blockIdx.x;
  int limit = ((nA + ROWCH - 1) / ROWCH) * ROWCH;
  int tid = threadIdx.x;

  if (ai >= nA) {
    if (ai < limit && tid < 64) {     // zero-pad fragment rows
      short8 z;
      #pragma unroll
      for (int j = 0; j < 8; ++j) z[j] = 0;
      *reinterpret_cast<short8*>(ws->aHiT + ((size_t)tid*ROWS_MAX + ai)*8) = z;
      *reinterpret_cast<short8*>(ws->aLoT + ((size_t)tid*ROWS_MAX + ai)*8) = z;
    }
    return;
  }

  int p = ws->activeList[ai];
  if (tid < 64) {
    const float* src = enc + (size_t)p*ND + tid*8;
    float4 x0 = *reinterpret_cast<const float4*>(src);
    float4 x1 = *reinterpret_cast<const float4*>(src + 4);
    float xv[8] = {x0.x, x0.y, x0.z, x0.w, x1.x, x1.y, x1.z, x1.w};
    short8 h, l;
    #pragma unroll
    for (int j = 0; j < 8; ++j) {
      unsigned short hi = bf16_rne(xv[j]);
      float rem = xv[j] - __uint_as_float((unsigned)hi << 16);
      h[j] = (short)hi;
      l[j] = (short)bf16_rne(rem);
    }
    *reinterpret_cast<short8*>(ws->aHiT + ((size_t)tid*ROWS_MAX + ai)*8) = h;
    *reinterpret_cast<short8*>(ws->aLoT + ((size_t)tid*ROWS_MAX + ai)*8) = l;
  }

  int b = p >> 8, ts = p & (NTS-1);
  __shared__ float sN[SFD];
  __shared__ float sPart[4*64];
  __shared__ float rS[4], rQ[4];

  for (int j = tid; j < SFD; j += 256) {
    int k = j / NF, f = j - k*NF;
    sN[j] = (feats[((size_t)b*NT + ts*NSTRIDE + k)*NF + f] - mean[f]) * istd[f];
  }
  __syncthreads();
  float s = 0.f, q = 0.f;
  for (int j = tid; j < SFD; j += 256) { float x = sN[j]; s += x; q += x*x; }
  for (int o = 32; o; o >>= 1) { s += __shfl_down(s, o); q += __shfl_down(q, o); }
  if ((tid & 63) == 0) { rS[tid>>6] = s; rQ[tid>>6] = q; }
  __syncthreads();
  float mu  = (rS[0]+rS[1]+rS[2]+rS[3]) * (1.f/SFD);
  float var = (rQ[0]+rQ[1]+rQ[2]+rQ[3]) * (1.f/SFD) - mu*mu;
  float inv = rsqrtf(var + LNEPS);
  for (int j = tid; j < SFD; j += 256) sN[j] = (sN[j]-mu)*inv;
  __syncthreads();
  {
    int j = tid & 63, part = tid >> 6;
    float a = 0.f;
    int i0 = part*80;
    for (int i = i0; i < i0+80; ++i) a = fmaf(sN[i], projw[i*64 + j], a);
    sPart[part*64 + j] = a;
  }
  __syncthreads();
  if (tid < 64)
    ws->lat[ai][tid] = sPart[tid] + sPart[64+tid] + sPart[128+tid] + sPart[192+tid];
}

// ---- codebook argmin, c-parallel, 16-way row-split; spread atomicMin ----
__global__ __launch_bounds__(256) void k_qdist(const float* __restrict__ emb, Ws* ws) {
  int nA = (int)ws->nA;
  if (nA == 0) return;
  int tid = threadIdx.x;
  int g = tid >> 6, lane = tid & 63;
  int c = blockIdx.x * 64 + lane;
  int per = (nA + QY - 1) / QY;
  int a0 = blockIdx.y * per;
  int a1 = min(nA, a0 + per);
  int slot = blockIdx.x & (QS-1);

  const float4* e4 = reinterpret_cast<const float4*>(emb + ((size_t)c*NG + g)*NE);
  float4 b0 = e4[0], b1 = e4[1], b2 = e4[2], b3 = e4[3];
  float n2 = b0.x*b0.x + b0.y*b0.y + b0.z*b0.z + b0.w*b0.w
           + b1.x*b1.x + b1.y*b1.y + b1.z*b1.z + b1.w*b1.w
           + b2.x*b2.x + b2.y*b2.y + b2.z*b2.z + b2.w*b2.w
           + b3.x*b3.x + b3.y*b3.y + b3.z*b3.z + b3.w*b3.w;

  __shared__ float sL[QCH][64];
  for (int base = a0; base < a1; base += QCH) {
    int cnt = min(QCH, a1 - base);
    __syncthreads();
    for (int i = tid; i < cnt*64; i += 256)
      (&sL[0][0])[i] = (&ws->lat[0][0])[(size_t)(base + (i >> 6))*64 + (i & 63)];
    __syncthreads();
    for (int i = 0; i < cnt; ++i) {
      const float* lp = &sL[i][g*NE];
      float dot = lp[0]*b0.x + lp[1]*b0.y + lp[2]*b0.z + lp[3]*b0.w
                + lp[4]*b1.x + lp[5]*b1.y + lp[6]*b1.z + lp[7]*b1.w
                + lp[8]*b2.x + lp[9]*b2.y + lp[10]*b2.z + lp[11]*b2.w
                + lp[12]*b3.x + lp[13]*b3.y + lp[14]*b3.z + lp[15]*b3.w;
      float d = n2 - 2.f*dot;
      float mv = d; int mc = c;
      #pragma unroll
      for (int off = 32; off; off >>= 1) {
        float ov = __shfl_xor(mv, off);
        int   oc = __shfl_xor(mc, off);
        if (ov < mv || (ov == mv && oc < mc)) { mv = ov; mc = oc; }
      }
      if (lane == 0) {
        unsigned long long key =
            ((unsigned long long)fkey_asc(mv) << 32) | (unsigned)mc;
        atomicMin(&ws->aminS[(size_t)((base + i)*NG + g)*QS + slot], key);
      }
    }
  }
}

// ---- extract targets + uniq bitmap from spread slots ----
__global__ void k_tgt(Ws* ws) {
  int i = blockIdx.x*256 + threadIdx.x;
  int nA = (int)ws->nA;
  if (i < nA*NG) {
    unsigned long long m = ws->aminS[(size_t)i*QS];
    #pragma unroll
    for (int s = 1; s < QS; ++s) {
      unsigned long long v = ws->aminS[(size_t)i*QS + s];
      if (v < m) m = v;
    }
    int c = (int)(unsigned)(m & 0xFFFFFFFFull);
    ws->targets[i] = c;
    atomicOr(&ws->bitmap[c >> 5], 1u << (c & 31));
  }
}

// ---- logits GEMM: W read+split exactly once (A-operand), enc fragment-order
// (B-operand), in-block K-split across waves for TLP, atomic-free epilogue ----
__global__ __launch_bounds__(512, 4) void k_logits_mfma(
    const float* __restrict__ W, const float* __restrict__ bias, Ws* ws) {
  const int nA = (int)ws->nA;
  if (nA == 0) return;
  const int nCh = (nA + ROWCH - 1) / ROWCH;
  const int tid = threadIdx.x;
  const int wave = tid >> 6, lane = tid & 63;
  const int sub = wave & 3, kh = wave >> 2;
  const int g = blockIdx.y;
  const int c0w = blockIdx.x * 64 + sub * 16;
  const int lo16 = lane & 15, hi4 = lane >> 4;
  const int cA = c0w + lo16;           // A-fragment column
  const int cOut0 = c0w + hi4*4;       // this lane's 4 output c's
  float bv[4];
  #pragma unroll
  for (int v = 0; v < 4; ++v) bv[v] = bias[g*NC + cOut0 + v];

  __shared__ f32x4 sAcc[4][MT][64];              // 36 KB k-half combine
  __shared__ float sEs[4][ROWCH];
  __shared__ unsigned long long sMx[4][ROWCH];

  for (int ch = 0; ch < nCh; ++ch) {
    const int r0 = ch * ROWCH;
    f32x4 acc[MT];
    #pragma unroll
    for (int mt = 0; mt < MT; ++mt) acc[mt] = (f32x4){0.f, 0.f, 0.f, 0.f};

    for (int ks = kh*8; ks < kh*8 + 8; ++ks) {
      short8 bh[MT], bl[MT];
      const size_t boff = ((size_t)(ks*4 + hi4)*ROWS_MAX + r0 + lo16)*8;
      #pragma unroll
      for (int mt = 0; mt < MT; ++mt) {
        bh[mt] = *reinterpret_cast<const short8*>(ws->aHiT + boff + (size_t)mt*128);
        bl[mt] = *reinterpret_cast<const short8*>(ws->aLoT + boff + (size_t)mt*128);
      }
      const float* wp = W + ((size_t)g*ND + ks*32 + hi4*8)*NC + cA;
      float wv[8];
      #pragma unroll
      for (int j = 0; j < 8; ++j) wv[j] = wp[(size_t)j*NC];
      short8 whi, wlo;
      #pragma unroll
      for (int j = 0; j < 8; ++j) {
        unsigned short h = bf16_rne(wv[j]);
        float rem = wv[j] - __uint_as_float((unsigned)h << 16);
        whi[j] = (short)h;
        wlo[j] = (short)bf16_rne(rem);
      }
      #pragma unroll
      for (int mt = 0; mt < MT; ++mt) {
        acc[mt] = __builtin_amdgcn_mfma_f32_16x16x32_bf16(whi, bh[mt], acc[mt], 0, 0, 0);
        acc[mt] = __builtin_amdgcn_mfma_f32_16x16x32_bf16(wlo, bh[mt], acc[mt], 0, 0, 0);
        acc[mt] = __builtin_amdgcn_mfma_f32_16x16x32_bf16(whi, bl[mt], acc[mt], 0, 0, 0);
      }
    }

    if (kh == 1) {
      #pragma unroll
      for (int mt = 0; mt < MT; ++mt) sAcc[sub][mt][lane] = acc[mt];
    }
    __syncthreads();

    if (kh == 0) {
      #pragma unroll
      for (int mt = 0; mt < MT; ++mt) {
        f32x4 oth = sAcc[sub][mt][lane];
        const int row = r0 + mt*16 + lo16;
        const int tgt = (row < nA) ? ws->targets[row*NG + g] : -1;
        float lv[4];
        #pragma unroll
        for (int v = 0; v < 4; ++v) lv[v] = (acc[mt][v] + oth[v]) + bv[v];
        #pragma unroll
        for (int v = 0; v < 4; ++v)
          if (tgt == cOut0 + v) ws->tLogit[row*NG + g] = lv[v];
        float es = expf(lv[0]) + expf(lv[1]) + expf(lv[2]) + expf(lv[3]);
        float mv = lv[0]; int mi = cOut0;
        if (lv[1] > mv) { mv = lv[1]; mi = cOut0+1; }
        if (lv[2] > mv) { mv = lv[2]; mi = cOut0+2; }
        if (lv[3] > mv) { mv = lv[3]; mi = cOut0+3; }
        #pragma unroll
        for (int off = 16; off <= 32; off <<= 1) {
          es += __shfl_xor(es, off);
          float ov = __shfl_xor(mv, off);
          int   oi = __shfl_xor(mi, off);
          if (ov > mv || (ov == mv && oi < mi)) { mv = ov; mi = oi; }
        }
        if (hi4 == 0) {
          sEs[sub][mt*16 + lo16] = es;
          unsigned key = __float_as_uint(mv);
          key = (key & 0x80000000u) ? ~key : (key | 0x80000000u);
          sMx[sub][mt*16 + lo16] = ((unsigned long long)key << 32)
                                 | (unsigned long long)(0xFFFFFFFFu - (unsigned)mi);
        }
      }
    }
    __syncthreads();
    if (tid < ROWCH) {
      float e = sEs[0][tid] + sEs[1][tid] + sEs[2][tid] + sEs[3][tid];
      unsigned long long m0 = sMx[0][tid], m1 = sMx[1][tid];
      unsigned long long m2 = sMx[2][tid], m3 = sMx[3][tid];
      unsigned long long ma = m0 > m1 ? m0 : m1;
      unsigned long long mb = m2 > m3 ? m2 : m3;
      unsigned long long mx = ma > mb ? ma : mb;
      int grow = r0 + tid;
      ws->part_se[g][grow][blockIdx.x] = e;
      ws->part_mx[g][grow][blockIdx.x] = mx;
    }
    __syncthreads();
  }
}

// ---- reduce 128 c-tile partials per (row,g): plain stores, no atomics ----
__global__ __launch_bounds__(256) void k_red_l(Ws* ws) {
  int nA = (int)ws->nA;
  int pair = blockIdx.x*4 + (threadIdx.x >> 6);
  int lane = threadIdx.x & 63;
  int row = pair >> 2, g = pair & 3;
  if (row >= nA) return;
  float e = ws->part_se[g][row][lane] + ws->part_se[g][row][lane + 64];
  unsigned long long a = ws->part_mx[g][row][lane];
  unsigned long long b = ws->part_mx[g][row][lane + 64];
  unsigned long long mx = a > b ? a : b;
  #pragma unroll
  for (int off = 32; off; off >>= 1) {
    e += __shfl_xor(e, off);
    unsigned long long o = __shfl_xor(mx, off);
    if (o > mx) mx = o;
  }
  if (lane == 0) {
    ws->sumExp[row*NG + g] = e;
    ws->amax[row*NG + g] = mx;
  }
}

// ======================= fallback fp32 path (round-1, proven) ==============
__global__ __launch_bounds__(256) void k_quant(
    const float* __restrict__ feats, const float* __restrict__ mean,
    const float* __restrict__ istd, const float* __restrict__ projw,
    const float* __restrict__ emb, Ws* ws) {
  if (blockIdx.x >= ws->nA) return;
  int ai = blockIdx.x;
  int p = ws->activeList[ai];
  int b = p >> 8, ts = p & (NTS-1);
  int tid = threadIdx.x;
  __shared__ float sN[SFD];
  __shared__ float sPart[4*64];
  __shared__ float sLat[NG*NE];
  __shared__ float sRedS[256];
  __shared__ int   sRedC[256];
  __shared__ float rS[4], rQ[4];
  __shared__ int   sTgt[NG];

  for (int j = tid; j < SFD; j += 256) {
    int k = j / NF, f = j - k*NF;
    sN[j] = (feats[((size_t)b*NT + ts*NSTRIDE + k)*NF + f] - mean[f]) * istd[f];
  }
  __syncthreads();
  float s = 0.f, q = 0.f;
  for (int j = tid; j < SFD; j += 256) { float x = sN[j]; s += x; q += x*x; }
  for (int o = 32; o; o >>= 1) { s += __shfl_down(s, o); q += __shfl_down(q, o); }
  if ((tid & 63) == 0) { rS[tid>>6] = s; rQ[tid>>6] = q; }
  __syncthreads();
  float mu  = (rS[0]+rS[1]+rS[2]+rS[3]) * (1.f/SFD);
  float var = (rQ[0]+rQ[1]+rQ[2]+rQ[3]) * (1.f/SFD) - mu*mu;
  float inv = rsqrtf(var + LNEPS);
  for (int j = tid; j < SFD; j += 256) sN[j] = (sN[j]-mu)*inv;
  __syncthreads();
  {
    int j = tid & 63, part = tid >> 6;
    float a = 0.f;
    int i0 = part*80;
    for (int i = i0; i < i0+80; ++i) a = fmaf(sN[i], projw[i*64 + j], a);
    sPart[part*64 + j] = a;
  }
  __syncthreads();
  if (tid < 64) sLat[tid] = sPart[tid] + sPart[64+tid] + sPart[128+tid] + sPart[192+tid];
  __syncthreads();

  for (int gg = 0; gg < NG; ++gg) {
    float lg[NE];
    #pragma unroll
    for (int e = 0; e < NE; ++e) lg[e] = sLat[gg*NE + e];
    float best = 3.4e38f; int bc = NC;
    for (int c = tid; c < NC; c += 256) {
      const float4* cb4 = reinterpret_cast<const float4*>(emb + ((size_t)c*NG + gg)*NE);
      float4 a0 = cb4[0], a1 = cb4[1], a2 = cb4[2], a3 = cb4[3];
      float dot = 0.f, n2 = 0.f;
      dot = fmaf(lg[0],  a0.x, dot); n2 = fmaf(a0.x, a0.x, n2);
      dot = fmaf(lg[1],  a0.y, dot); n2 = fmaf(a0.y, a0.y, n2);
      dot = fmaf(lg[2],  a0.z, dot); n2 = fmaf(a0.z, a0.z, n2);
      dot = fmaf(lg[3],  a0.w, dot); n2 = fmaf(a0.w, a0.w, n2);
      dot = fmaf(lg[4],  a1.x, dot); n2 = fmaf(a1.x, a1.x, n2);
      dot = fmaf(lg[5],  a1.y, dot); n2 = fmaf(a1.y, a1.y, n2);
      dot = fmaf(lg[6],  a1.z, dot); n2 = fmaf(a1.z, a1.z, n2);
      dot = fmaf(lg[7],  a1.w, dot); n2 = fmaf(a1.w, a1.w, n2);
      dot = fmaf(lg[8],  a2.x, dot); n2 = fmaf(a2.x, a2.x, n2);
      dot = fmaf(lg[9],  a2.y, dot); n2 = fmaf(a2.y, a2.y, n2);
      dot = fmaf(lg[10], a2.z, dot); n2 = fmaf(a2.z, a2.z, n2);
      dot = fmaf(lg[11], a2.w, dot); n2 = fmaf(a2.w, a2.w, n2);
      dot = fmaf(lg[12], a3.x, dot); n2 = fmaf(a3.x, a3.x, n2);
      dot = fmaf(lg[13], a3.y, dot); n2 = fmaf(a3.y, a3.y, n2);
      dot = fmaf(lg[14], a3.z, dot); n2 = fmaf(a3.z, a3.z, n2);
      dot = fmaf(lg[15], a3.w, dot); n2 = fmaf(a3.w, a3.w, n2);
      float sc = n2 - 2.f*dot;
      if (sc < best) { best = sc; bc = c; }
    }
    sRedS[tid] = best; sRedC[tid] = bc;
    __syncthreads();
    for (int off = 128; off; off >>= 1) {
      if (tid < off) {
        float os = sRedS[tid+off]; int oc = sRedC[tid+off];
        if (os < sRedS[tid] || (os == sRedS[tid] && oc < sRedC[tid])) {
          sRedS[tid] = os; sRedC[tid] = oc;
        }
      }
      __syncthreads();
    }
    if (tid == 0) sTgt[gg] = sRedC[0];
    __syncthreads();
  }
  if (tid < NG) {
    int c = sTgt[tid];
    ws->targets[ai*NG + tid] = c;
    atomicOr(&ws->bitmap[c >> 5], 1u << (c & 31));
  }
}

__global__ __launch_bounds__(256) void k_logits(
    const float* __restrict__ W, const float* __restrict__ bias,
    const float* __restrict__ enc, Ws* ws) {
  const int nA = (int)ws->nA;
  if (nA == 0) return;
  const int nCh = (nA + PCH - 1) / PCH;
  const int g = blockIdx.y;
  const int cbase = blockIdx.x * TCC + threadIdx.x * CPT;
  const float* __restrict__ Wg = W + (size_t)g*ND*NC;
  const float b0 = bias[g*NC + cbase + 0];
  const float b1 = bias[g*NC + cbase + 1];
  const float b2 = bias[g*NC + cbase + 2];
  const float b3 = bias[g*NC + cbase + 3];
  __shared__ float4 sEnc[PCH][ND/4];
  __shared__ int sP[PCH];

  for (int ch = blockIdx.z; ch < nCh; ch += PB) {
    if (threadIdx.x < PCH) {
      int ai = ch*PCH + threadIdx.x;
      sP[threadIdx.x] = (ai < nA) ? ws->activeList[ai] : -1;
    }
    __syncthreads();
    for (int i = threadIdx.x; i < PCH*(ND/4); i += 256) {
      int qq = i >> 7, r = i & 127;
      int p = sP[qq];
      sEnc[qq][r] = (p >= 0) ? reinterpret_cast<const float4*>(enc)[p*(ND/4) + r]
                             : make_float4(0.f, 0.f, 0.f, 0.f);
    }
    __syncthreads();

    float acc[PCH][CPT];
    #pragma unroll
    for (int qq = 0; qq < PCH; ++qq)
      #pragma unroll
      for (int j = 0; j < CPT; ++j) acc[qq][j] = 0.f;
    for (int d = 0; d < ND; d += 4) {
      const float* wp = Wg + (size_t)d*NC + cbase;
      float4 w0 = *reinterpret_cast<const float4*>(wp);
      float4 w1 = *reinterpret_cast<const float4*>(wp + NC);
      float4 w2 = *reinterpret_cast<const float4*>(wp + 2*NC);
      float4 w3 = *reinterpret_cast<const float4*>(wp + 3*NC);
      int dq = d >> 2;
      #pragma unroll
      for (int qq = 0; qq < PCH; ++qq) {
        float4 e = sEnc[qq][dq];
        acc[qq][0] = fmaf(e.x, w0.x, acc[qq][0]);
        acc[qq][1] = fmaf(e.x, w0.y, acc[qq][1]);
        acc[qq][2] = fmaf(e.x, w0.z, acc[qq][2]);
        acc[qq][3] = fmaf(e.x, w0.w, acc[qq][3]);
        acc[qq][0] = fmaf(e.y, w1.x, acc[qq][0]);
        acc[qq][1] = fmaf(e.y, w1.y, acc[qq][1]);
        acc[qq][2] = fmaf(e.y, w1.z, acc[qq][2]);
        acc[qq][3] = fmaf(e.y, w1.w, acc[qq][3]);
        acc[qq][0] = fmaf(e.z, w2.x, acc[qq][0]);
        acc[qq][1] = fmaf(e.z, w2.y, acc[qq][1]);
        acc[qq][2] = fmaf(e.z, w2.z, acc[qq][2]);
        acc[qq][3] = fmaf(e.z, w2.w, acc[qq][3]);
        acc[qq][0] = fmaf(e.w, w3.x, acc[qq][0]);
        acc[qq][1] = fmaf(e.w, w3.y, acc[qq][1]);
        acc[qq][2] = fmaf(e.w, w3.z, acc[qq][2]);
        acc[qq][3] = fmaf(e.w, w3.w, acc[qq][3]);
      }
    }

    #pragma unroll
    for (int qq = 0; qq < PCH; ++qq) {
      int ai = ch*PCH + qq;
      if (ai < nA) {
        float l0 = acc[qq][0] + b0;
        float l1 = acc[qq][1] + b1;
        float l2 = acc[qq][2] + b2;
        float l3 = acc[qq][3] + b3;
        int tgt = ws->targets[ai*NG + g];
        if ((unsigned)(tgt - cbase) < (unsigned)CPT) {
          float tv = (tgt == cbase) ? l0 : (tgt == cbase+1) ? l1
                   : (tgt == cbase+2) ? l2 : l3;
          ws->tLogit[ai*NG + g] = tv;
        }
        float es = expf(l0) + expf(l1) + expf(l2) + expf(l3);
        float mv = l0; int mi = cbase;
        if (l1 > mv) { mv = l1; mi = cbase+1; }
        if (l2 > mv) { mv = l2; mi = cbase+2; }
        if (l3 > mv) { mv = l3; mi = cbase+3; }
        for (int o = 32; o; o >>= 1) {
          es += __shfl_down(es, o);
          float ov = __shfl_down(mv, o);
          int   oi = __shfl_down(mi, o);
          if (ov > mv || (ov == mv && oi < mi)) { mv = ov; mi = oi; }
        }
        if ((threadIdx.x & 63) == 0) {
          atomicAdd(&ws->sumExp[ai*NG + g], es);
          unsigned key = __float_as_uint(mv);
          key = (key & 0x80000000u) ? ~key : (key | 0x80000000u);
          unsigned long long pk =
              ((unsigned long long)key << 32) |
              (unsigned long long)(0xFFFFFFFFu - (unsigned)mi);
          atomicMax(&ws->amax[ai*NG + g], pk);
        }
      }
    }
    __syncthreads();
  }
}
// ======================= end fallback =======================================

// ---- final scalar assembly ----
__global__ __launch_bounds__(256) void k_final(Ws* ws, float* __restrict__ out) {
  int tid = threadIdx.x;
  int nA = (int)ws->nA;
  float sumPer = 0.f, sumCorr = 0.f;
  for (int i = tid; i < nA*NG; i += 256) {
    sumPer += logf(ws->sumExp[i]) - ws->tLogit[i];
    unsigned long long pk = ws->amax[i];
    int mi = (int)(0xFFFFFFFFu - (unsigned)(pk & 0xFFFFFFFFull));
    if (mi == ws->targets[i]) sumCorr += 1.f;
  }
  unsigned w = ws->bitmap[tid];
  if (tid == 0 && nA < NP) w |= 1u;
  int uniq = __popc(w);

  __shared__ float rs[4], rc[4]; __shared__ int ru[4];
  float s1 = sumPer, s2 = sumCorr; int s3 = uniq;
  for (int o = 32; o; o >>= 1) {
    s1 += __shfl_down(s1, o);
    s2 += __shfl_down(s2, o);
    s3 += __shfl_down(s3, o);
  }
  if ((tid & 63) == 0) { rs[tid>>6] = s1; rc[tid>>6] = s2; ru[tid>>6] = s3; }
  __syncthreads();
  if (tid == 0) {
    float sp = rs[0]+rs[1]+rs[2]+rs[3];
    float sc = rc[0]+rc[1]+rc[2]+rc[3];
    int   un = ru[0]+ru[1]+ru[2]+ru[3];
    float pen   = ws->penSum / (float)(NB*NT*NF);
    float denom = (float)nA + 1e-5f;
    float nc    = (float)(nA * NG);
    out[0] = sp / (denom * (float)NG) + FREG * pen;
    out[1] = sc / nc;
    out[2] = pen;
    out[3] = nc;
    out[4] = (float)un;
  }
}

extern "C" void kernel_launch(void* const* d_in, const int* in_sizes, int n_in,
                              void* d_out, int out_size, void* d_ws, size_t ws_size,
                              hipStream_t stream) {
  const float* feats = (const float*)d_in[0];
  const int*   lens  = (const int*)d_in[1];
  const unsigned char* masks = (const unsigned char*)d_in[2];
  const float* mean  = (const float*)d_in[4];
  const float* istd  = (const float*)d_in[5];
  const float* projw = (const float*)d_in[6];
  const float* emb   = (const float*)d_in[7];
  const float* W     = (const float*)d_in[8];
  const float* bias  = (const float*)d_in[9];
  const float* enc   = (const float*)d_in[10];
  Ws* ws = (Ws*)d_ws;
  float* out = (float*)d_out;

  bool big = ws_size >= sizeof(Ws);
  size_t zr = offsetof(Ws, aminS);
  hipMemsetAsync(d_ws, 0, (big || ws_size >= zr) ? zr : ws_size, stream);

  k_prologue<<<256, 256, 0, stream>>>(feats, mean, istd, masks, lens,
                                      big ? 1 : 0, ws);

  if (big) {
    k_latprep<<<ROWS_MAX, 256, 0, stream>>>(feats, mean, istd, projw, enc, ws);
    k_qdist<<<dim3(NC/64, QY), 256, 0, stream>>>(emb, ws);
    k_tgt<<<NP*NG/256, 256, 0, stream>>>(ws);
    k_logits_mfma<<<dim3(CT, NG), 512, 0, stream>>>(W, bias, ws);
    k_red_l<<<NP, 256, 0, stream>>>(ws);
  } else {
    k_quant<<<NP, 256, 0, stream>>>(feats, mean, istd, projw, emb, ws);
    k_logits<<<dim3(NC/TCC, NG, PB), 256, 0, stream>>>(W, bias, enc, ws);
  }
  k_final<<<1, 256, 0, stream>>>(ws, out);
}